// Round 1
// baseline (1507.684 us; speedup 1.0000x reference)
//
#include <hip/hip_runtime.h>

// ---------------------------------------------------------------------------
// TTT layer forward: B=4, L=8192, D=1024, H=16, HD=64, C=64, NC=128
// Pipeline: cvt -> fused QKV+lr GEMM (bf16 MFMA) -> elementwise norms ->
//           sequential TTT scan (MFMA, W state in registers) -> post-LN ->
//           output GEMM.
// ---------------------------------------------------------------------------

typedef __attribute__((ext_vector_type(8))) short short8;
typedef __attribute__((ext_vector_type(4))) float f32x4;
typedef __attribute__((ext_vector_type(4))) unsigned short us4;

__device__ __forceinline__ float bf2f(unsigned short s) {
  union { unsigned int u; float f; } c;
  c.u = ((unsigned int)s) << 16;
  return c.f;
}
__device__ __forceinline__ unsigned short f2bf(float f) {
  union { float f; unsigned int u; } c;
  c.f = f;
  unsigned int u = c.u;
  return (unsigned short)((u + 0x7FFFu + ((u >> 16) & 1u)) >> 16);
}

__device__ __forceinline__ void gload_lds16(const void* g, void* l) {
  __builtin_amdgcn_global_load_lds(
      (const __attribute__((address_space(1))) unsigned int*)g,
      (__attribute__((address_space(3))) unsigned int*)l, 16, 0, 0);
}

// ---------------- conversion kernels ----------------
__global__ __launch_bounds__(256) void cvt_f32_bf16(
    const float* __restrict__ in, unsigned short* __restrict__ out, long n) {
  long i = ((long)blockIdx.x * 256 + threadIdx.x) * 4;
  if (i + 3 < n) {
    float4 v = *(const float4*)&in[i];
    us4 o = { f2bf(v.x), f2bf(v.y), f2bf(v.z), f2bf(v.w) };
    *(us4*)&out[i] = o;
  }
}

// Wcat rows: [0,1024)=wq, [1024,2048)=wk, [2048,3072)=wv, [3072,3088)=lr_w, rest 0
__global__ __launch_bounds__(256) void build_wcat(
    const float* __restrict__ wq, const float* __restrict__ wk,
    const float* __restrict__ wv, const float* __restrict__ lrw,
    const float* __restrict__ wqb, const float* __restrict__ wkb,
    const float* __restrict__ wvb, const float* __restrict__ lrb,
    unsigned short* __restrict__ Wcat, float* __restrict__ biasc) {
  int i = blockIdx.x * 256 + threadIdx.x;   // 0 .. 3200*1024-1
  int row = i >> 10, col = i & 1023;
  float v;
  if (row < 1024)      v = wq[i];
  else if (row < 2048) v = wk[i - 1048576];
  else if (row < 3072) v = wv[i - 2097152];
  else if (row < 3088) v = lrw[(row - 3072) * 1024 + col];
  else                 v = 0.f;
  Wcat[i] = f2bf(v);
  if (i < 3200) {
    float bv;
    if (i < 1024)      bv = wqb[i];
    else if (i < 2048) bv = wkb[i - 1024];
    else if (i < 3072) bv = wvb[i - 2048];
    else if (i < 3088) bv = lrb[i - 3072];
    else               bv = 0.f;
    biasc[i] = bv;
  }
}

// ---------------- bf16 GEMM: C[M,N] = A[M,K] @ B[N,K]^T + bias ----------------
// m97 structure: 128x128 tile, BK=64, 4 waves (2x2), global_load_lds staging.
template <int WRITE_BF16>
__global__ __launch_bounds__(256) void gemm_bt(
    const unsigned short* __restrict__ A, const unsigned short* __restrict__ B,
    const float* __restrict__ bias, void* __restrict__ Cout,
    int M, int N, int K) {
  __shared__ __align__(16) unsigned short As[128 * 64];
  __shared__ __align__(16) unsigned short Bs[128 * 64];
  const int tid = threadIdx.x;
  const int lane = tid & 63;
  const int wid = tid >> 6;
  const int wr = wid >> 1, wc = wid & 1;
  const int l15 = lane & 15, lg = lane >> 4;
  const long m0 = (long)blockIdx.y * 128;
  const long n0 = (long)blockIdx.x * 128;

  f32x4 acc[4][4];
#pragma unroll
  for (int m = 0; m < 4; m++)
#pragma unroll
    for (int n = 0; n < 4; n++) acc[m][n] = (f32x4){0.f, 0.f, 0.f, 0.f};

  const int obase = wid * 4096 + lane * 16;  // byte offset within 16KB tile

  for (int kt = 0; kt < K; kt += 64) {
#pragma unroll
    for (int j = 0; j < 4; ++j) {
      int o = obase + j * 1024;
      int r = o >> 7;        // 128 B per row
      int cb = o & 127;      // byte within row
      const char* ga = (const char*)(A + (m0 + r) * (long)K + kt) + cb;
      const char* gb = (const char*)(B + (n0 + r) * (long)K + kt) + cb;
      gload_lds16(ga, (char*)As + wid * 4096 + j * 1024);
      gload_lds16(gb, (char*)Bs + wid * 4096 + j * 1024);
    }
    __syncthreads();
    short8 bfrag[4][2];
#pragma unroll
    for (int n = 0; n < 4; ++n)
#pragma unroll
      for (int kk = 0; kk < 2; ++kk)
        bfrag[n][kk] =
            *(const short8*)&Bs[(wc * 64 + n * 16 + l15) * 64 + kk * 32 + lg * 8];
#pragma unroll
    for (int m = 0; m < 4; ++m) {
#pragma unroll
      for (int kk = 0; kk < 2; ++kk) {
        short8 af =
            *(const short8*)&As[(wr * 64 + m * 16 + l15) * 64 + kk * 32 + lg * 8];
#pragma unroll
        for (int n = 0; n < 4; ++n)
          acc[m][n] = __builtin_amdgcn_mfma_f32_16x16x32_bf16(af, bfrag[n][kk],
                                                              acc[m][n], 0, 0, 0);
      }
    }
    __syncthreads();
  }
#pragma unroll
  for (int m = 0; m < 4; ++m) {
    long r0 = m0 + wr * 64 + m * 16 + lg * 4;
#pragma unroll
    for (int n = 0; n < 4; ++n) {
      long c = n0 + wc * 64 + n * 16 + l15;
      float bv = bias ? bias[c] : 0.f;
#pragma unroll
      for (int j = 0; j < 4; ++j) {
        float v = acc[m][n][j] + bv;
        if (WRITE_BF16)
          ((unsigned short*)Cout)[(r0 + j) * (long)N + c] = f2bf(v);
        else
          ((float*)Cout)[(r0 + j) * (long)N + c] = v;
      }
    }
  }
}

// ---------------- stage 2: l2norm Q/K, LN(V-K)+K, eta ----------------
__global__ __launch_bounds__(256) void stage2(
    const unsigned short* __restrict__ QKVL, const float* __restrict__ tnw,
    const float* __restrict__ tnb, unsigned short* __restrict__ XQn,
    unsigned short* __restrict__ XKn, unsigned short* __restrict__ XVn,
    float* __restrict__ eta_buf) {
  int wid = threadIdx.x >> 6, lane = threadIdx.x & 63;
  long idx = (long)blockIdx.x * 4 + wid;  // flat (t*16 + h)
  long t = idx >> 4;
  int h = (int)(idx & 15);
  size_t base = (size_t)t * 3200;
  float q = bf2f(QKVL[base + h * 64 + lane]);
  float k = bf2f(QKVL[base + 1024 + h * 64 + lane]);
  float v = bf2f(QKVL[base + 2048 + h * 64 + lane]);
  float sq = q * q, sk = k * k;
#pragma unroll
  for (int o = 1; o < 64; o <<= 1) {
    sq += __shfl_xor(sq, o);
    sk += __shfl_xor(sk, o);
  }
  float qn = q / fmaxf(sqrtf(sq), 1e-12f);
  float kn = k / fmaxf(sqrtf(sk), 1e-12f);
  float d = v - kn;
  float s1 = d, s2 = d * d;
#pragma unroll
  for (int o = 1; o < 64; o <<= 1) {
    s1 += __shfl_xor(s1, o);
    s2 += __shfl_xor(s2, o);
  }
  float mu = s1 * 0.015625f;
  float var1 = fmaxf(s2 - 64.f * mu * mu, 0.f) * (1.f / 63.f);  // ddof=1
  float sd = sqrtf(var1);
  float xvn = tnw[h * 64 + lane] * ((d - mu) / (sd + 1e-5f)) +
              tnb[h * 64 + lane] + kn;
  size_t ob = (size_t)t * 1024 + h * 64 + lane;
  XQn[ob] = f2bf(qn);
  XKn[ob] = f2bf(kn);
  XVn[ob] = f2bf(xvn);
  if (lane == 0) {
    float logit = bf2f(QKVL[base + 3072 + h]);  // includes ttt_lr_bias
    float sig = 1.f / (1.f + expf(-logit));
    long bb = t >> 13, l = t & 8191;
    eta_buf[(size_t)(bb * 16 + h) * 8192 + l] = sig * (1.f / 4096.f);
  }
}

// ---------------- stage 3: sequential TTT scan ----------------
// one block per (b,h); W state in registers (MFMA C/D layout), 128 chunks.
__global__ __launch_bounds__(256, 1) void ttt_scan(
    const unsigned short* __restrict__ XQ, const unsigned short* __restrict__ XK,
    const unsigned short* __restrict__ XV, const float* __restrict__ eta_buf,
    const float* __restrict__ W1, const float* __restrict__ b1,
    const float* __restrict__ tnw, const float* __restrict__ tnb,
    float* __restrict__ y) {
  const int bh = blockIdx.x;
  const int b = bh >> 4, h = bh & 15;
  const int tid = threadIdx.x;
  const int lane = tid & 63, wid = tid >> 6;
  const int l15 = lane & 15, lg = lane >> 4;

  // stride-72 padding kills the 128B-row bank conflicts on ds_read_b128
  __shared__ __align__(16) unsigned short xq_s[64 * 72];
  __shared__ __align__(16) unsigned short xk_s[64 * 72];
  __shared__ __align__(16) unsigned short tg_s[64 * 72];  // tgt, then -Gc
  __shared__ __align__(16) unsigned short WT_b[64 * 72];  // W^T bf16
  __shared__ __align__(16) unsigned short gradT[64 * 72]; // grad^T bf16
  __shared__ __align__(16) unsigned short xkTe[64 * 72];  // -eta[c]*xk[c][d] at [d][c]
  __shared__ float bst[64];
  __shared__ float eta_s[64];
  __shared__ float gw_s[64], gb_s[64];
  __shared__ float bpart[4][64];

  // W state in regs, C/D layout: Wreg[n][j] = W[d][e], d=wid*16+lg*4+j, e=n*16+l15
  f32x4 Wreg[4];
#pragma unroll
  for (int n = 0; n < 4; ++n)
#pragma unroll
    for (int j = 0; j < 4; ++j) {
      int d = wid * 16 + lg * 4 + j, e = n * 16 + l15;
      float w = W1[h * 4096 + d * 64 + e];
      Wreg[n][j] = w;
      WT_b[e * 72 + d] = f2bf(w);
    }
  if (tid < 64) {
    bst[tid] = b1[h * 64 + tid];
    gw_s[tid] = tnw[h * 64 + tid];
    gb_s[tid] = tnb[h * 64 + tid];
  }
  __syncthreads();

  const size_t tokb = (size_t)b * 8192;
  const int col0 = h * 64;

  for (int nc = 0; nc < 128; ++nc) {
    const int l0 = nc * 64;
    // --- step 1: stage xq, xk, tgt=xv-xk, eta ---
#pragma unroll
    for (int it = 0; it < 2; ++it) {
      int cid = tid + it * 256;
      int r = cid >> 3, c8 = (cid & 7) * 8;
      size_t g = (tokb + l0 + r) * 1024 + col0 + c8;
      short8 vq = *(const short8*)&XQ[g];
      short8 vk = *(const short8*)&XK[g];
      short8 vv = *(const short8*)&XV[g];
      *(short8*)&xq_s[r * 72 + c8] = vq;
      *(short8*)&xk_s[r * 72 + c8] = vk;
      short8 vt;
#pragma unroll
      for (int u = 0; u < 8; ++u)
        vt[u] = (short)f2bf(bf2f((unsigned short)vv[u]) -
                            bf2f((unsigned short)vk[u]));
      *(short8*)&tg_s[r * 72 + c8] = vt;
    }
    if (tid < 64) eta_s[tid] = eta_buf[(size_t)bh * 8192 + l0 + tid];
    __syncthreads();
    // --- step 2: xkTe[d][c] = -eta[c]*xk[c][d]  (read at step 6) ---
#pragma unroll
    for (int it = 0; it < 16; ++it) {
      int c = wid * 16 + it;
      int d = lane;
      xkTe[d * 72 + c] = f2bf(-eta_s[c] * bf2f(xk_s[c * 72 + d]));
    }
    // --- step 3: Z1 = xk@W + b  and  Attn = xq@xk^T ---
    f32x4 accZ[4], accA[4];
#pragma unroll
    for (int n = 0; n < 4; ++n) {
      float bv = bst[n * 16 + l15];
      accZ[n] = (f32x4){bv, bv, bv, bv};
      accA[n] = (f32x4){0.f, 0.f, 0.f, 0.f};
    }
#pragma unroll
    for (int kk = 0; kk < 2; ++kk) {
      const int ko = kk * 32 + lg * 8;
      short8 a_xk = *(const short8*)&xk_s[(wid * 16 + l15) * 72 + ko];
      short8 a_xq = *(const short8*)&xq_s[(wid * 16 + l15) * 72 + ko];
#pragma unroll
      for (int n = 0; n < 4; ++n) {
        short8 b_w = *(const short8*)&WT_b[(n * 16 + l15) * 72 + ko];
        short8 b_k = *(const short8*)&xk_s[(n * 16 + l15) * 72 + ko];
        accZ[n] = __builtin_amdgcn_mfma_f32_16x16x32_bf16(a_xk, b_w, accZ[n], 0, 0, 0);
        accA[n] = __builtin_amdgcn_mfma_f32_16x16x32_bf16(a_xq, b_k, accA[n], 0, 0, 0);
      }
    }
    // --- step 4: LN-l2 backward, rows via 16-lane shuffle groups ---
#pragma unroll
    for (int j = 0; j < 4; ++j) {
      const int r = wid * 16 + lg * 4 + j;
      float z[4], s1 = 0.f, s2 = 0.f;
#pragma unroll
      for (int n = 0; n < 4; ++n) {
        z[n] = accZ[n][j];
        s1 += z[n];
        s2 += z[n] * z[n];
      }
#pragma unroll
      for (int o = 1; o < 16; o <<= 1) {
        s1 += __shfl_xor(s1, o);
        s2 += __shfl_xor(s2, o);
      }
      float mu = s1 * 0.015625f;
      float var = s2 * 0.015625f - mu * mu;
      float rstd = rsqrtf(var + 1e-6f);
      float xh[4], gx[4], s3 = 0.f, s4 = 0.f;
#pragma unroll
      for (int n = 0; n < 4; ++n) {
        int e = n * 16 + l15;
        xh[n] = (z[n] - mu) * rstd;
        float tg = bf2f(tg_s[r * 72 + e]);
        float go = gw_s[e] * xh[n] + gb_s[e] - tg;
        gx[n] = go * gw_s[e];
        s3 += gx[n];
        s4 += gx[n] * xh[n];
      }
#pragma unroll
      for (int o = 1; o < 16; o <<= 1) {
        s3 += __shfl_xor(s3, o);
        s4 += __shfl_xor(s4, o);
      }
#pragma unroll
      for (int n = 0; n < 4; ++n) {
        int e = n * 16 + l15;
        float gr = (64.f * gx[n] - s3 - xh[n] * s4) * rstd * 0.015625f;
        gradT[e * 72 + r] = f2bf(gr);
      }
    }
    // --- step 5: Gc[i][j] = -(j<=i)*eta[j]*(1+Attn[i][j]) into tg_s ---
    // (safe alias: each address read in step 4 and written here by same thread)
#pragma unroll
    for (int j = 0; j < 4; ++j) {
      const int r = wid * 16 + lg * 4 + j;
#pragma unroll
      for (int n = 0; n < 4; ++n) {
        int cj = n * 16 + l15;
        float v = (cj <= r) ? (-eta_s[cj] * (1.f + accA[n][j])) : 0.f;
        tg_s[r * 72 + cj] = f2bf(v);
      }
    }
    __syncthreads();
    // --- step 6: Z1_bar = xq@W + Gc@grad + b ;  W' = W + (-eta.xk)^T@grad ---
    f32x4 accZb[4], accW[4];
#pragma unroll
    for (int n = 0; n < 4; ++n) {
      float bv = bst[n * 16 + l15];
      accZb[n] = (f32x4){bv, bv, bv, bv};
      accW[n] = Wreg[n];
    }
#pragma unroll
    for (int kk = 0; kk < 2; ++kk) {
      const int ko = kk * 32 + lg * 8;
      short8 a_xq = *(const short8*)&xq_s[(wid * 16 + l15) * 72 + ko];
      short8 a_gc = *(const short8*)&tg_s[(wid * 16 + l15) * 72 + ko];
      short8 a_ke = *(const short8*)&xkTe[(wid * 16 + l15) * 72 + ko];
#pragma unroll
      for (int n = 0; n < 4; ++n) {
        short8 b_w = *(const short8*)&WT_b[(n * 16 + l15) * 72 + ko];
        short8 b_g = *(const short8*)&gradT[(n * 16 + l15) * 72 + ko];
        accZb[n] = __builtin_amdgcn_mfma_f32_16x16x32_bf16(a_xq, b_w, accZb[n], 0, 0, 0);
        accZb[n] = __builtin_amdgcn_mfma_f32_16x16x32_bf16(a_gc, b_g, accZb[n], 0, 0, 0);
        accW[n] = __builtin_amdgcn_mfma_f32_16x16x32_bf16(a_ke, b_g, accW[n], 0, 0, 0);
      }
    }
    // b_new partials: bpart[cg][e] = sum_{c in cg} eta[c]*grad[c][e]
    {
      int e = tid & 63, cg = tid >> 6;
      float s = 0.f;
#pragma unroll
      for (int c = 0; c < 16; ++c)
        s += eta_s[cg * 16 + c] * bf2f(gradT[e * 72 + cg * 16 + c]);
      bpart[cg][e] = s;
    }
    __syncthreads();
    // --- step 7: commit W, b; out = xq + LN(Z1_bar) ---
#pragma unroll
    for (int n = 0; n < 4; ++n) {
      Wreg[n] = accW[n];
#pragma unroll
      for (int j = 0; j < 4; ++j) {
        int d = wid * 16 + lg * 4 + j, e = n * 16 + l15;
        WT_b[e * 72 + d] = f2bf(accW[n][j]);
      }
    }
    if (tid < 64)
      bst[tid] -= bpart[0][tid] + bpart[1][tid] + bpart[2][tid] + bpart[3][tid];
#pragma unroll
    for (int j = 0; j < 4; ++j) {
      const int r = wid * 16 + lg * 4 + j;
      float z[4], s1 = 0.f, s2 = 0.f;
#pragma unroll
      for (int n = 0; n < 4; ++n) {
        z[n] = accZb[n][j];
        s1 += z[n];
        s2 += z[n] * z[n];
      }
#pragma unroll
      for (int o = 1; o < 16; o <<= 1) {
        s1 += __shfl_xor(s1, o);
        s2 += __shfl_xor(s2, o);
      }
      float mu = s1 * 0.015625f;
      float var = s2 * 0.015625f - mu * mu;
      float rstd = rsqrtf(var + 1e-6f);
      size_t gbase = (tokb + l0 + r) * 1024 + col0;
#pragma unroll
      for (int n = 0; n < 4; ++n) {
        int e = n * 16 + l15;
        float ov = bf2f(xq_s[r * 72 + e]) + gw_s[e] * ((z[n] - mu) * rstd) + gb_s[e];
        y[gbase + e] = ov;
      }
    }
    __syncthreads();
  }
}

// ---------------- stage 4: post layernorm over D=1024 ----------------
__global__ __launch_bounds__(256) void postnorm(
    const float* __restrict__ yv, const float* __restrict__ pw,
    const float* __restrict__ pb, unsigned short* __restrict__ yn) {
  int t = blockIdx.x;
  int tid = threadIdx.x, lane = tid & 63, wid = tid >> 6;
  const float* row = yv + (size_t)t * 1024;
  float4 v = *(const float4*)&row[tid * 4];
  float s1 = v.x + v.y + v.z + v.w;
  float s2 = v.x * v.x + v.y * v.y + v.z * v.z + v.w * v.w;
#pragma unroll
  for (int o = 1; o < 64; o <<= 1) {
    s1 += __shfl_xor(s1, o);
    s2 += __shfl_xor(s2, o);
  }
  __shared__ float r1[4], r2[4];
  if (lane == 0) {
    r1[wid] = s1;
    r2[wid] = s2;
  }
  __syncthreads();
  s1 = r1[0] + r1[1] + r1[2] + r1[3];
  s2 = r2[0] + r2[1] + r2[2] + r2[3];
  float mu = s1 * (1.f / 1024.f);
  float var = s2 * (1.f / 1024.f) - mu * mu;
  float rstd = rsqrtf(var + 1e-6f);
  int c = tid * 4;
  us4 o4 = {f2bf(pw[c] * ((v.x - mu) * rstd) + pb[c]),
            f2bf(pw[c + 1] * ((v.y - mu) * rstd) + pb[c + 1]),
            f2bf(pw[c + 2] * ((v.z - mu) * rstd) + pb[c + 2]),
            f2bf(pw[c + 3] * ((v.w - mu) * rstd) + pb[c + 3])};
  *(us4*)&yn[(size_t)t * 1024 + c] = o4;
}

// ---------------------------------------------------------------------------
extern "C" void kernel_launch(void* const* d_in, const int* in_sizes, int n_in,
                              void* d_out, int out_size, void* d_ws,
                              size_t ws_size, hipStream_t stream) {
  const float* hs  = (const float*)d_in[0];
  const float* wqw = (const float*)d_in[1];
  const float* wqb = (const float*)d_in[2];
  const float* wkw = (const float*)d_in[3];
  const float* wkb = (const float*)d_in[4];
  const float* wvw = (const float*)d_in[5];
  const float* wvb = (const float*)d_in[6];
  const float* wow = (const float*)d_in[7];
  const float* wob = (const float*)d_in[8];
  const float* tnw = (const float*)d_in[9];
  const float* tnb = (const float*)d_in[10];
  const float* lrw = (const float*)d_in[11];
  const float* lrb = (const float*)d_in[12];
  const float* W1  = (const float*)d_in[13];
  const float* b1  = (const float*)d_in[14];
  const float* pnw = (const float*)d_in[15];
  const float* pnb = (const float*)d_in[16];

  // workspace layout (bytes)
  const size_t OFF_WCAT  = 67108864;                 // after hs_bf (64MB)
  const size_t OFF_BIASC = OFF_WCAT + 6553600;
  const size_t OFF_WOBF  = OFF_BIASC + 12800;
  const size_t OFF_QKVL  = OFF_WOBF + 2097152;       // 209,715,200 B region
  const size_t OFF_XQ    = OFF_QKVL + 209715200;
  const size_t OFF_XK    = OFF_XQ + 67108864;
  const size_t OFF_XV    = OFF_XK + 67108864;
  const size_t OFF_ETA   = OFF_XV + 67108864;
  const size_t NEEDED    = OFF_ETA + 2097152;
  if (ws_size < NEEDED) return;  // fail loudly (output stays poisoned)

  char* ws = (char*)d_ws;
  unsigned short* hs_bf = (unsigned short*)ws;
  unsigned short* Wcat  = (unsigned short*)(ws + OFF_WCAT);
  float* biasc          = (float*)(ws + OFF_BIASC);
  unsigned short* wo_bf = (unsigned short*)(ws + OFF_WOBF);
  unsigned short* QKVL  = (unsigned short*)(ws + OFF_QKVL);
  float* yv             = (float*)(ws + OFF_QKVL);            // alias (after stage2)
  unsigned short* ynorm = (unsigned short*)(ws + OFF_QKVL + 134217728);
  unsigned short* XQn   = (unsigned short*)(ws + OFF_XQ);
  unsigned short* XKn   = (unsigned short*)(ws + OFF_XK);
  unsigned short* XVn   = (unsigned short*)(ws + OFF_XV);
  float* eta_buf        = (float*)(ws + OFF_ETA);

  cvt_f32_bf16<<<32768, 256, 0, stream>>>(hs, hs_bf, 33554432L);
  build_wcat<<<12800, 256, 0, stream>>>(wqw, wkw, wvw, lrw, wqb, wkb, wvb, lrb,
                                        Wcat, biasc);
  cvt_f32_bf16<<<1024, 256, 0, stream>>>(wow, wo_bf, 1048576L);
  gemm_bt<1><<<dim3(25, 256), 256, 0, stream>>>(hs_bf, Wcat, biasc, QKVL,
                                                32768, 3200, 1024);
  stage2<<<131072, 256, 0, stream>>>(QKVL, tnw, tnb, XQn, XKn, XVn, eta_buf);
  ttt_scan<<<64, 256, 0, stream>>>(XQn, XKn, XVn, eta_buf, W1, b1, tnw, tnb, yv);
  postnorm<<<32768, 256, 0, stream>>>(yv, pnw, pnb, ynorm);
  gemm_bt<0><<<dim3(8, 256), 256, 0, stream>>>(ynorm, wo_bf, wob, d_out,
                                               32768, 1024, 1024);
}

// Round 2
// 1211.613 us; speedup vs baseline: 1.2444x; 1.2444x over previous
//
#include <hip/hip_runtime.h>

// ---------------------------------------------------------------------------
// TTT layer forward: B=4, L=8192, D=1024, H=16, HD=64, C=64, NC=128
// ---------------------------------------------------------------------------

typedef __attribute__((ext_vector_type(8))) short short8;
typedef __attribute__((ext_vector_type(4))) float f32x4;
typedef __attribute__((ext_vector_type(4))) unsigned short us4;

__device__ __forceinline__ float bf2f(unsigned short s) {
  union { unsigned int u; float f; } c;
  c.u = ((unsigned int)s) << 16;
  return c.f;
}
__device__ __forceinline__ unsigned short f2bf(float f) {
  union { float f; unsigned int u; } c;
  c.f = f;
  unsigned int u = c.u;
  return (unsigned short)((u + 0x7FFFu + ((u >> 16) & 1u)) >> 16);
}

__device__ __forceinline__ void gload_lds16(const void* g, void* l) {
  __builtin_amdgcn_global_load_lds(
      (const __attribute__((address_space(1))) unsigned int*)g,
      (__attribute__((address_space(3))) unsigned int*)l, 16, 0, 0);
}

// ---------------- conversion kernels ----------------
__global__ __launch_bounds__(256) void cvt_f32_bf16(
    const float* __restrict__ in, unsigned short* __restrict__ out, long n) {
  long i = ((long)blockIdx.x * 256 + threadIdx.x) * 4;
  if (i + 3 < n) {
    float4 v = *(const float4*)&in[i];
    us4 o = { f2bf(v.x), f2bf(v.y), f2bf(v.z), f2bf(v.w) };
    *(us4*)&out[i] = o;
  }
}

__global__ __launch_bounds__(256) void build_wcat(
    const float* __restrict__ wq, const float* __restrict__ wk,
    const float* __restrict__ wv, const float* __restrict__ lrw,
    const float* __restrict__ wqb, const float* __restrict__ wkb,
    const float* __restrict__ wvb, const float* __restrict__ lrb,
    unsigned short* __restrict__ Wcat, float* __restrict__ biasc) {
  int i = blockIdx.x * 256 + threadIdx.x;
  int row = i >> 10, col = i & 1023;
  float v;
  if (row < 1024)      v = wq[i];
  else if (row < 2048) v = wk[i - 1048576];
  else if (row < 3072) v = wv[i - 2097152];
  else if (row < 3088) v = lrw[(row - 3072) * 1024 + col];
  else                 v = 0.f;
  Wcat[i] = f2bf(v);
  if (i < 3200) {
    float bv;
    if (i < 1024)      bv = wqb[i];
    else if (i < 2048) bv = wkb[i - 1024];
    else if (i < 3072) bv = wvb[i - 2048];
    else if (i < 3088) bv = lrb[i - 3072];
    else               bv = 0.f;
    biasc[i] = bv;
  }
}

// ---------------- bf16 GEMM: C[M,N] = A[M,K] @ B[N,K]^T + bias ----------------
template <int WRITE_BF16>
__global__ __launch_bounds__(256) void gemm_bt(
    const unsigned short* __restrict__ A, const unsigned short* __restrict__ B,
    const float* __restrict__ bias, void* __restrict__ Cout,
    int M, int N, int K) {
  __shared__ __align__(16) unsigned short As[128 * 64];
  __shared__ __align__(16) unsigned short Bs[128 * 64];
  const int tid = threadIdx.x;
  const int lane = tid & 63;
  const int wid = tid >> 6;
  const int wr = wid >> 1, wc = wid & 1;
  const int l15 = lane & 15, lg = lane >> 4;
  const long m0 = (long)blockIdx.y * 128;
  const long n0 = (long)blockIdx.x * 128;

  f32x4 acc[4][4];
#pragma unroll
  for (int m = 0; m < 4; m++)
#pragma unroll
    for (int n = 0; n < 4; n++) acc[m][n] = (f32x4){0.f, 0.f, 0.f, 0.f};

  const int obase = wid * 4096 + lane * 16;

  for (int kt = 0; kt < K; kt += 64) {
#pragma unroll
    for (int j = 0; j < 4; ++j) {
      int o = obase + j * 1024;
      int r = o >> 7;
      int cb = o & 127;
      const char* ga = (const char*)(A + (m0 + r) * (long)K + kt) + cb;
      const char* gb = (const char*)(B + (n0 + r) * (long)K + kt) + cb;
      gload_lds16(ga, (char*)As + wid * 4096 + j * 1024);
      gload_lds16(gb, (char*)Bs + wid * 4096 + j * 1024);
    }
    __syncthreads();
    short8 bfrag[4][2];
#pragma unroll
    for (int n = 0; n < 4; ++n)
#pragma unroll
      for (int kk = 0; kk < 2; ++kk)
        bfrag[n][kk] =
            *(const short8*)&Bs[(wc * 64 + n * 16 + l15) * 64 + kk * 32 + lg * 8];
#pragma unroll
    for (int m = 0; m < 4; ++m) {
#pragma unroll
      for (int kk = 0; kk < 2; ++kk) {
        short8 af =
            *(const short8*)&As[(wr * 64 + m * 16 + l15) * 64 + kk * 32 + lg * 8];
#pragma unroll
        for (int n = 0; n < 4; ++n)
          acc[m][n] = __builtin_amdgcn_mfma_f32_16x16x32_bf16(af, bfrag[n][kk],
                                                              acc[m][n], 0, 0, 0);
      }
    }
    __syncthreads();
  }
#pragma unroll
  for (int m = 0; m < 4; ++m) {
    long r0 = m0 + wr * 64 + m * 16 + lg * 4;
#pragma unroll
    for (int n = 0; n < 4; ++n) {
      long c = n0 + wc * 64 + n * 16 + l15;
      float bv = bias ? bias[c] : 0.f;
#pragma unroll
      for (int j = 0; j < 4; ++j) {
        float v = acc[m][n][j] + bv;
        if (WRITE_BF16)
          ((unsigned short*)Cout)[(r0 + j) * (long)N + c] = f2bf(v);
        else
          ((float*)Cout)[(r0 + j) * (long)N + c] = v;
      }
    }
  }
}

// ---------------- stage 2: l2norm Q/K, tgt = LN(V-K) part, eta ----------------
__global__ __launch_bounds__(256) void stage2(
    const unsigned short* __restrict__ QKVL, const float* __restrict__ tnw,
    const float* __restrict__ tnb, unsigned short* __restrict__ XQn,
    unsigned short* __restrict__ XKn, unsigned short* __restrict__ TGT,
    float* __restrict__ eta_buf) {
  int wid = threadIdx.x >> 6, lane = threadIdx.x & 63;
  long idx = (long)blockIdx.x * 4 + wid;
  long t = idx >> 4;
  int h = (int)(idx & 15);
  size_t base = (size_t)t * 3200;
  float q = bf2f(QKVL[base + h * 64 + lane]);
  float k = bf2f(QKVL[base + 1024 + h * 64 + lane]);
  float v = bf2f(QKVL[base + 2048 + h * 64 + lane]);
  float sq = q * q, sk = k * k;
#pragma unroll
  for (int o = 1; o < 64; o <<= 1) {
    sq += __shfl_xor(sq, o);
    sk += __shfl_xor(sk, o);
  }
  float qn = q / fmaxf(sqrtf(sq), 1e-12f);
  float kn = k / fmaxf(sqrtf(sk), 1e-12f);
  float d = v - kn;
  float s1 = d, s2 = d * d;
#pragma unroll
  for (int o = 1; o < 64; o <<= 1) {
    s1 += __shfl_xor(s1, o);
    s2 += __shfl_xor(s2, o);
  }
  float mu = s1 * 0.015625f;
  float var1 = fmaxf(s2 - 64.f * mu * mu, 0.f) * (1.f / 63.f);  // ddof=1
  float sd = sqrtf(var1);
  // tgt = XV - XK = tnw*norm + tnb (the "+ XK" cancels in the scan)
  float tgt = tnw[h * 64 + lane] * ((d - mu) / (sd + 1e-5f)) + tnb[h * 64 + lane];
  size_t ob = (size_t)t * 1024 + h * 64 + lane;
  XQn[ob] = f2bf(qn);
  XKn[ob] = f2bf(kn);
  TGT[ob] = f2bf(tgt);
  if (lane == 0) {
    float logit = bf2f(QKVL[base + 3072 + h]);
    float sig = 1.f / (1.f + expf(-logit));
    long bb = t >> 13, l = t & 8191;
    eta_buf[(size_t)(bb * 16 + h) * 8192 + l] = sig * (1.f / 4096.f);
  }
}

// ---------------- stage 3: sequential TTT scan ----------------
// One block per (b,h) chain: 8 waves, role-split.
//   A group (waves 0-3): Z1 = xk@W, LN-bwd -> gradT, Z1_bar, LN-fwd -> y
//   B group (waves 4-7): xkTe transpose, Attn, Gc, W-update, bpart, WT write
// 3 barriers per chunk; next chunk's xq/xk/tgt prefetched into registers.
__global__ __launch_bounds__(512, 1) void ttt_scan(
    const unsigned short* __restrict__ XQ, const unsigned short* __restrict__ XK,
    const unsigned short* __restrict__ TG, const float* __restrict__ eta_buf,
    const float* __restrict__ W1, const float* __restrict__ b1,
    const float* __restrict__ tnw, const float* __restrict__ tnb,
    float* __restrict__ y) {
  const int bh = blockIdx.x;
  const int b = bh >> 4, h = bh & 15;
  const int tid = threadIdx.x;
  const int lane = tid & 63, wid = tid >> 6;  // wid 0..7
  const bool isA = wid < 4;
  const int q = wid & 3;
  const int l15 = lane & 15, lg = lane >> 4;

  __shared__ __align__(16) unsigned short xq_s[64 * 72];
  __shared__ __align__(16) unsigned short xk_s[64 * 72];
  __shared__ __align__(16) unsigned short tg_s[64 * 72];   // tgt (A-private read)
  __shared__ __align__(16) unsigned short gc_s[64 * 72];   // Gc (B writes ph1, A reads ph2)
  __shared__ __align__(16) unsigned short WT_b[2][64 * 72];// W^T ping-pong
  __shared__ __align__(16) unsigned short gradT[64 * 72];  // grad^T
  __shared__ __align__(16) unsigned short xkTe[64 * 72];   // -eta[c]*xk[c][d] at [d][c]
  __shared__ float bst[64];
  __shared__ float eta_s[64];
  __shared__ float gw_s[64], gb_s[64];
  __shared__ float bpart[4][64];

  const size_t tokb = (size_t)b * 8192;
  const int col0 = h * 64;

  // prefetch registers (A: xq+tgt, B: xk [+eta on wave 4])
  short8 pA0[2], pA1[2], pB0[2];
  float peta = 0.f;

  // ---- prologue: prefetch chunk 0 ----
  {
    if (isA) {
#pragma unroll
      for (int j = 0; j < 2; ++j) {
        int rr = q * 16 + j * 8 + (lane >> 3);
        size_t g = (tokb + rr) * 1024 + col0 + (lane & 7) * 8;
        pA0[j] = *(const short8*)&XQ[g];
        pA1[j] = *(const short8*)&TG[g];
      }
    } else {
#pragma unroll
      for (int j = 0; j < 2; ++j) {
        int rr = q * 16 + j * 8 + (lane >> 3);
        size_t g = (tokb + rr) * 1024 + col0 + (lane & 7) * 8;
        pB0[j] = *(const short8*)&XK[g];
      }
      if (wid == 4) peta = eta_buf[(size_t)bh * 8192 + lane];
    }
  }

  // ---- init state ----
  f32x4 Wreg[4];
  if (!isA) {
#pragma unroll
    for (int n = 0; n < 4; ++n)
#pragma unroll
      for (int j = 0; j < 4; ++j) {
        int d = q * 16 + lg * 4 + j, e = n * 16 + l15;
        float w = W1[h * 4096 + d * 64 + e];
        Wreg[n][j] = w;
        WT_b[0][e * 72 + d] = f2bf(w);
      }
    if (wid == 4) bst[lane] = b1[h * 64 + lane];
  } else {
    if (wid == 0) {
      gw_s[lane] = tnw[h * 64 + lane];
      gb_s[lane] = tnb[h * 64 + lane];
    }
  }
  __syncthreads();

  for (int nc = 0; nc < 128; ++nc) {
    const unsigned short* WTc = WT_b[nc & 1];
    unsigned short* WTn = WT_b[(nc + 1) & 1];

    // ---- commit prefetched registers to LDS ----
    if (isA) {
#pragma unroll
      for (int j = 0; j < 2; ++j) {
        int rr = q * 16 + j * 8 + (lane >> 3), c8 = (lane & 7) * 8;
        *(short8*)&xq_s[rr * 72 + c8] = pA0[j];
        *(short8*)&tg_s[rr * 72 + c8] = pA1[j];
      }
    } else {
#pragma unroll
      for (int j = 0; j < 2; ++j) {
        int rr = q * 16 + j * 8 + (lane >> 3), c8 = (lane & 7) * 8;
        *(short8*)&xk_s[rr * 72 + c8] = pB0[j];
      }
      if (wid == 4) eta_s[lane] = peta;
    }
    __syncthreads();  // B1

    // ---- issue prefetch for chunk nc+1 (drained at B2) ----
    if (nc + 1 < 128) {
      const int l0n = (nc + 1) * 64;
      if (isA) {
#pragma unroll
        for (int j = 0; j < 2; ++j) {
          int rr = q * 16 + j * 8 + (lane >> 3);
          size_t g = (tokb + l0n + rr) * 1024 + col0 + (lane & 7) * 8;
          pA0[j] = *(const short8*)&XQ[g];
          pA1[j] = *(const short8*)&TG[g];
        }
      } else {
#pragma unroll
        for (int j = 0; j < 2; ++j) {
          int rr = q * 16 + j * 8 + (lane >> 3);
          size_t g = (tokb + l0n + rr) * 1024 + col0 + (lane & 7) * 8;
          pB0[j] = *(const short8*)&XK[g];
        }
        if (wid == 4) peta = eta_buf[(size_t)bh * 8192 + l0n + lane];
      }
    }

    if (isA) {
      // ---- A phase 1: Z1 = xk@W + b, then LN-l2 backward -> gradT ----
      f32x4 accZ[4];
#pragma unroll
      for (int n = 0; n < 4; ++n) {
        float bv = bst[n * 16 + l15];
        accZ[n] = (f32x4){bv, bv, bv, bv};
      }
#pragma unroll
      for (int kk = 0; kk < 2; ++kk) {
        const int ko = kk * 32 + lg * 8;
        short8 a_xk = *(const short8*)&xk_s[(q * 16 + l15) * 72 + ko];
#pragma unroll
        for (int n = 0; n < 4; ++n) {
          short8 b_w = *(const short8*)&WTc[(n * 16 + l15) * 72 + ko];
          accZ[n] = __builtin_amdgcn_mfma_f32_16x16x32_bf16(a_xk, b_w, accZ[n], 0, 0, 0);
        }
      }
#pragma unroll
      for (int j = 0; j < 4; ++j) {
        const int r = q * 16 + lg * 4 + j;
        float z[4], s1 = 0.f, s2 = 0.f;
#pragma unroll
        for (int n = 0; n < 4; ++n) {
          z[n] = accZ[n][j];
          s1 += z[n];
          s2 += z[n] * z[n];
        }
#pragma unroll
        for (int o = 1; o < 16; o <<= 1) {
          s1 += __shfl_xor(s1, o);
          s2 += __shfl_xor(s2, o);
        }
        float mu = s1 * 0.015625f;
        float var = s2 * 0.015625f - mu * mu;
        float rstd = rsqrtf(var + 1e-6f);
        float xh[4], gx[4], s3 = 0.f, s4 = 0.f;
#pragma unroll
        for (int n = 0; n < 4; ++n) {
          int e = n * 16 + l15;
          xh[n] = (z[n] - mu) * rstd;
          float tg = bf2f(tg_s[r * 72 + e]);
          float go = gw_s[e] * xh[n] + gb_s[e] - tg;
          gx[n] = go * gw_s[e];
          s3 += gx[n];
          s4 += gx[n] * xh[n];
        }
#pragma unroll
        for (int o = 1; o < 16; o <<= 1) {
          s3 += __shfl_xor(s3, o);
          s4 += __shfl_xor(s4, o);
        }
#pragma unroll
        for (int n = 0; n < 4; ++n) {
          int e = n * 16 + l15;
          float gr = (64.f * gx[n] - s3 - xh[n] * s4) * rstd * 0.015625f;
          gradT[e * 72 + r] = f2bf(gr);
        }
      }
    } else {
      // ---- B phase 1: xkTe transpose, Attn = xq@xk^T, Gc ----
#pragma unroll
      for (int it = 0; it < 16; ++it) {
        int c = q * 16 + it;
        xkTe[lane * 72 + c] = f2bf(-eta_s[c] * bf2f(xk_s[c * 72 + lane]));
      }
      f32x4 accA[4];
#pragma unroll
      for (int n = 0; n < 4; ++n) accA[n] = (f32x4){0.f, 0.f, 0.f, 0.f};
#pragma unroll
      for (int kk = 0; kk < 2; ++kk) {
        const int ko = kk * 32 + lg * 8;
        short8 a_xq = *(const short8*)&xq_s[(q * 16 + l15) * 72 + ko];
#pragma unroll
        for (int n = 0; n < 4; ++n) {
          short8 b_k = *(const short8*)&xk_s[(n * 16 + l15) * 72 + ko];
          accA[n] = __builtin_amdgcn_mfma_f32_16x16x32_bf16(a_xq, b_k, accA[n], 0, 0, 0);
        }
      }
#pragma unroll
      for (int j = 0; j < 4; ++j) {
        const int r = q * 16 + lg * 4 + j;
#pragma unroll
        for (int n = 0; n < 4; ++n) {
          int cj = n * 16 + l15;
          float v = (cj <= r) ? (-eta_s[cj] * (1.f + accA[n][j])) : 0.f;
          gc_s[r * 72 + cj] = f2bf(v);
        }
      }
    }
    __syncthreads();  // B2

    if (isA) {
      // ---- A phase 2: Z1_bar = xq@W + Gc@grad + b; LN-fwd; y ----
      f32x4 accZb[4];
#pragma unroll
      for (int n = 0; n < 4; ++n) {
        float bv = bst[n * 16 + l15];
        accZb[n] = (f32x4){bv, bv, bv, bv};
      }
#pragma unroll
      for (int kk = 0; kk < 2; ++kk) {
        const int ko = kk * 32 + lg * 8;
        short8 a_xq = *(const short8*)&xq_s[(q * 16 + l15) * 72 + ko];
        short8 a_gc = *(const short8*)&gc_s[(q * 16 + l15) * 72 + ko];
#pragma unroll
        for (int n = 0; n < 4; ++n) {
          short8 b_w = *(const short8*)&WTc[(n * 16 + l15) * 72 + ko];
          short8 b_g = *(const short8*)&gradT[(n * 16 + l15) * 72 + ko];
          accZb[n] = __builtin_amdgcn_mfma_f32_16x16x32_bf16(a_xq, b_w, accZb[n], 0, 0, 0);
          accZb[n] = __builtin_amdgcn_mfma_f32_16x16x32_bf16(a_gc, b_g, accZb[n], 0, 0, 0);
        }
      }
#pragma unroll
      for (int j = 0; j < 4; ++j) {
        const int r = q * 16 + lg * 4 + j;
        float z[4], s1 = 0.f, s2 = 0.f;
#pragma unroll
        for (int n = 0; n < 4; ++n) {
          z[n] = accZb[n][j];
          s1 += z[n];
          s2 += z[n] * z[n];
        }
#pragma unroll
        for (int o = 1; o < 16; o <<= 1) {
          s1 += __shfl_xor(s1, o);
          s2 += __shfl_xor(s2, o);
        }
        float mu = s1 * 0.015625f;
        float var = s2 * 0.015625f - mu * mu;
        float rstd = rsqrtf(var + 1e-6f);
        size_t gbase = (tokb + nc * 64 + r) * 1024 + col0;
#pragma unroll
        for (int n = 0; n < 4; ++n) {
          int e = n * 16 + l15;
          float ov = bf2f(xq_s[r * 72 + e]) + gw_s[e] * ((z[n] - mu) * rstd) + gb_s[e];
          y[gbase + e] = ov;
        }
      }
    } else {
      // ---- B phase 2: W' = W + xkTe@grad; bpart; write new W^T ----
      f32x4 accW[4];
#pragma unroll
      for (int n = 0; n < 4; ++n) accW[n] = Wreg[n];
#pragma unroll
      for (int kk = 0; kk < 2; ++kk) {
        const int ko = kk * 32 + lg * 8;
        short8 a_ke = *(const short8*)&xkTe[(q * 16 + l15) * 72 + ko];
#pragma unroll
        for (int n = 0; n < 4; ++n) {
          short8 b_g = *(const short8*)&gradT[(n * 16 + l15) * 72 + ko];
          accW[n] = __builtin_amdgcn_mfma_f32_16x16x32_bf16(a_ke, b_g, accW[n], 0, 0, 0);
        }
      }
#pragma unroll
      for (int n = 0; n < 4; ++n) {
        Wreg[n] = accW[n];
#pragma unroll
        for (int j = 0; j < 4; ++j) {
          int d = q * 16 + lg * 4 + j, e = n * 16 + l15;
          WTn[e * 72 + d] = f2bf(accW[n][j]);
        }
      }
      {
        float s = 0.f;
#pragma unroll
        for (int c = 0; c < 16; ++c)
          s += eta_s[q * 16 + c] * bf2f(gradT[lane * 72 + q * 16 + c]);
        bpart[q][lane] = s;
      }
    }
    __syncthreads();  // B3

    if (wid == 4)
      bst[lane] -= bpart[0][lane] + bpart[1][lane] + bpart[2][lane] + bpart[3][lane];
  }
}

// ---------------- stage 4: post layernorm over D=1024 ----------------
__global__ __launch_bounds__(256) void postnorm(
    const float* __restrict__ yv, const float* __restrict__ pw,
    const float* __restrict__ pb, unsigned short* __restrict__ yn) {
  int t = blockIdx.x;
  int tid = threadIdx.x, lane = tid & 63, wid = tid >> 6;
  const float* row = yv + (size_t)t * 1024;
  float4 v = *(const float4*)&row[tid * 4];
  float s1 = v.x + v.y + v.z + v.w;
  float s2 = v.x * v.x + v.y * v.y + v.z * v.z + v.w * v.w;
#pragma unroll
  for (int o = 1; o < 64; o <<= 1) {
    s1 += __shfl_xor(s1, o);
    s2 += __shfl_xor(s2, o);
  }
  __shared__ float r1[4], r2[4];
  if (lane == 0) {
    r1[wid] = s1;
    r2[wid] = s2;
  }
  __syncthreads();
  s1 = r1[0] + r1[1] + r1[2] + r1[3];
  s2 = r2[0] + r2[1] + r2[2] + r2[3];
  float mu = s1 * (1.f / 1024.f);
  float var = s2 * (1.f / 1024.f) - mu * mu;
  float rstd = rsqrtf(var + 1e-6f);
  int c = tid * 4;
  us4 o4 = {f2bf(pw[c] * ((v.x - mu) * rstd) + pb[c]),
            f2bf(pw[c + 1] * ((v.y - mu) * rstd) + pb[c + 1]),
            f2bf(pw[c + 2] * ((v.z - mu) * rstd) + pb[c + 2]),
            f2bf(pw[c + 3] * ((v.w - mu) * rstd) + pb[c + 3])};
  *(us4*)&yn[(size_t)t * 1024 + c] = o4;
}

// ---------------------------------------------------------------------------
extern "C" void kernel_launch(void* const* d_in, const int* in_sizes, int n_in,
                              void* d_out, int out_size, void* d_ws,
                              size_t ws_size, hipStream_t stream) {
  const float* hs  = (const float*)d_in[0];
  const float* wqw = (const float*)d_in[1];
  const float* wqb = (const float*)d_in[2];
  const float* wkw = (const float*)d_in[3];
  const float* wkb = (const float*)d_in[4];
  const float* wvw = (const float*)d_in[5];
  const float* wvb = (const float*)d_in[6];
  const float* wow = (const float*)d_in[7];
  const float* wob = (const float*)d_in[8];
  const float* tnw = (const float*)d_in[9];
  const float* tnb = (const float*)d_in[10];
  const float* lrw = (const float*)d_in[11];
  const float* lrb = (const float*)d_in[12];
  const float* W1  = (const float*)d_in[13];
  const float* b1  = (const float*)d_in[14];
  const float* pnw = (const float*)d_in[15];
  const float* pnb = (const float*)d_in[16];

  const size_t OFF_WCAT  = 67108864;
  const size_t OFF_BIASC = OFF_WCAT + 6553600;
  const size_t OFF_WOBF  = OFF_BIASC + 12800;
  const size_t OFF_QKVL  = OFF_WOBF + 2097152;
  const size_t OFF_XQ    = OFF_QKVL + 209715200;
  const size_t OFF_XK    = OFF_XQ + 67108864;
  const size_t OFF_XV    = OFF_XK + 67108864;
  const size_t OFF_ETA   = OFF_XV + 67108864;
  const size_t NEEDED    = OFF_ETA + 2097152;
  if (ws_size < NEEDED) return;

  char* ws = (char*)d_ws;
  unsigned short* hs_bf = (unsigned short*)ws;
  unsigned short* Wcat  = (unsigned short*)(ws + OFF_WCAT);
  float* biasc          = (float*)(ws + OFF_BIASC);
  unsigned short* wo_bf = (unsigned short*)(ws + OFF_WOBF);
  unsigned short* QKVL  = (unsigned short*)(ws + OFF_QKVL);
  float* yv             = (float*)(ws + OFF_QKVL);             // alias (after stage2)
  unsigned short* ynorm = (unsigned short*)(ws + OFF_QKVL + 134217728);
  unsigned short* XQn   = (unsigned short*)(ws + OFF_XQ);
  unsigned short* XKn   = (unsigned short*)(ws + OFF_XK);
  unsigned short* TGT   = (unsigned short*)(ws + OFF_XV);
  float* eta_buf        = (float*)(ws + OFF_ETA);

  cvt_f32_bf16<<<32768, 256, 0, stream>>>(hs, hs_bf, 33554432L);
  build_wcat<<<12800, 256, 0, stream>>>(wqw, wkw, wvw, lrw, wqb, wkb, wvb, lrb,
                                        Wcat, biasc);
  cvt_f32_bf16<<<1024, 256, 0, stream>>>(wow, wo_bf, 1048576L);
  gemm_bt<1><<<dim3(25, 256), 256, 0, stream>>>(hs_bf, Wcat, biasc, QKVL,
                                                32768, 3200, 1024);
  stage2<<<131072, 256, 0, stream>>>(QKVL, tnw, tnb, XQn, XKn, TGT, eta_buf);
  ttt_scan<<<64, 512, 0, stream>>>(XQn, XKn, TGT, eta_buf, W1, b1, tnw, tnb, yv);
  postnorm<<<32768, 256, 0, stream>>>(yv, pnw, pnb, ynorm);
  gemm_bt<0><<<dim3(8, 256), 256, 0, stream>>>(ynorm, wo_bf, wob, d_out,
                                               32768, 1024, 1024);
}

// Round 3
// 1110.776 us; speedup vs baseline: 1.3573x; 1.0908x over previous
//
#include <hip/hip_runtime.h>

// ---------------------------------------------------------------------------
// TTT layer forward: B=4, L=8192, D=1024, H=16, HD=64, C=64, NC=128
// ---------------------------------------------------------------------------

typedef __attribute__((ext_vector_type(8))) short short8;
typedef __attribute__((ext_vector_type(4))) float f32x4;
typedef __attribute__((ext_vector_type(4))) unsigned short us4;

__device__ __forceinline__ float bf2f(unsigned short s) {
  union { unsigned int u; float f; } c;
  c.u = ((unsigned int)s) << 16;
  return c.f;
}
__device__ __forceinline__ unsigned short f2bf(float f) {
  union { float f; unsigned int u; } c;
  c.f = f;
  unsigned int u = c.u;
  return (unsigned short)((u + 0x7FFFu + ((u >> 16) & 1u)) >> 16);
}

__device__ __forceinline__ void gload_lds16(const void* g, void* l) {
  __builtin_amdgcn_global_load_lds(
      (const __attribute__((address_space(1))) unsigned int*)g,
      (__attribute__((address_space(3))) unsigned int*)l, 16, 0, 0);
}

// 16-lane sum reduction entirely on the VALU pipe via DPP:
// xor1 (quad_perm [1,0,3,2]), xor2 ([2,3,0,1]), row_half_mirror, row_mirror.
__device__ __forceinline__ float dpp16_sum(float x) {
  int v = __float_as_int(x);
  x += __int_as_float(__builtin_amdgcn_update_dpp(v, v, 0xB1, 0xF, 0xF, true));
  v = __float_as_int(x);
  x += __int_as_float(__builtin_amdgcn_update_dpp(v, v, 0x4E, 0xF, 0xF, true));
  v = __float_as_int(x);
  x += __int_as_float(__builtin_amdgcn_update_dpp(v, v, 0x141, 0xF, 0xF, true));
  v = __float_as_int(x);
  x += __int_as_float(__builtin_amdgcn_update_dpp(v, v, 0x140, 0xF, 0xF, true));
  return x;
}

// Raw barrier: waits only LDS ops (lgkmcnt), NEVER vmcnt -> outstanding
// global y-stores / prefetch loads stay in flight across the barrier.
__device__ __forceinline__ void barrier_fast() {
  __builtin_amdgcn_sched_barrier(0);
  asm volatile("s_waitcnt lgkmcnt(0)" ::: "memory");
  __builtin_amdgcn_s_barrier();
  asm volatile("" ::: "memory");
  __builtin_amdgcn_sched_barrier(0);
}

// ---------------- conversion kernels ----------------
__global__ __launch_bounds__(256) void cvt_f32_bf16(
    const float* __restrict__ in, unsigned short* __restrict__ out, long n) {
  long i = ((long)blockIdx.x * 256 + threadIdx.x) * 4;
  if (i + 3 < n) {
    float4 v = *(const float4*)&in[i];
    us4 o = { f2bf(v.x), f2bf(v.y), f2bf(v.z), f2bf(v.w) };
    *(us4*)&out[i] = o;
  }
}

__global__ __launch_bounds__(256) void build_wcat(
    const float* __restrict__ wq, const float* __restrict__ wk,
    const float* __restrict__ wv, const float* __restrict__ lrw,
    const float* __restrict__ wqb, const float* __restrict__ wkb,
    const float* __restrict__ wvb, const float* __restrict__ lrb,
    unsigned short* __restrict__ Wcat, float* __restrict__ biasc) {
  int i = blockIdx.x * 256 + threadIdx.x;
  int row = i >> 10, col = i & 1023;
  float v;
  if (row < 1024)      v = wq[i];
  else if (row < 2048) v = wk[i - 1048576];
  else if (row < 3072) v = wv[i - 2097152];
  else if (row < 3088) v = lrw[(row - 3072) * 1024 + col];
  else                 v = 0.f;
  Wcat[i] = f2bf(v);
  if (i < 3200) {
    float bv;
    if (i < 1024)      bv = wqb[i];
    else if (i < 2048) bv = wkb[i - 1024];
    else if (i < 3072) bv = wvb[i - 2048];
    else if (i < 3088) bv = lrb[i - 3072];
    else               bv = 0.f;
    biasc[i] = bv;
  }
}

// ---------------- bf16 GEMM: C[M,N] = A[M,K] @ B[N,K]^T + bias ----------------
template <int WRITE_BF16>
__global__ __launch_bounds__(256) void gemm_bt(
    const unsigned short* __restrict__ A, const unsigned short* __restrict__ B,
    const float* __restrict__ bias, void* __restrict__ Cout,
    int M, int N, int K) {
  __shared__ __align__(16) unsigned short As[128 * 64];
  __shared__ __align__(16) unsigned short Bs[128 * 64];
  const int tid = threadIdx.x;
  const int lane = tid & 63;
  const int wid = tid >> 6;
  const int wr = wid >> 1, wc = wid & 1;
  const int l15 = lane & 15, lg = lane >> 4;
  const long m0 = (long)blockIdx.y * 128;
  const long n0 = (long)blockIdx.x * 128;

  f32x4 acc[4][4];
#pragma unroll
  for (int m = 0; m < 4; m++)
#pragma unroll
    for (int n = 0; n < 4; n++) acc[m][n] = (f32x4){0.f, 0.f, 0.f, 0.f};

  const int obase = wid * 4096 + lane * 16;

  for (int kt = 0; kt < K; kt += 64) {
#pragma unroll
    for (int j = 0; j < 4; ++j) {
      int o = obase + j * 1024;
      int r = o >> 7;
      int cb = o & 127;
      const char* ga = (const char*)(A + (m0 + r) * (long)K + kt) + cb;
      const char* gb = (const char*)(B + (n0 + r) * (long)K + kt) + cb;
      gload_lds16(ga, (char*)As + wid * 4096 + j * 1024);
      gload_lds16(gb, (char*)Bs + wid * 4096 + j * 1024);
    }
    __syncthreads();
    short8 bfrag[4][2];
#pragma unroll
    for (int n = 0; n < 4; ++n)
#pragma unroll
      for (int kk = 0; kk < 2; ++kk)
        bfrag[n][kk] =
            *(const short8*)&Bs[(wc * 64 + n * 16 + l15) * 64 + kk * 32 + lg * 8];
#pragma unroll
    for (int m = 0; m < 4; ++m) {
#pragma unroll
      for (int kk = 0; kk < 2; ++kk) {
        short8 af =
            *(const short8*)&As[(wr * 64 + m * 16 + l15) * 64 + kk * 32 + lg * 8];
#pragma unroll
        for (int n = 0; n < 4; ++n)
          acc[m][n] = __builtin_amdgcn_mfma_f32_16x16x32_bf16(af, bfrag[n][kk],
                                                              acc[m][n], 0, 0, 0);
      }
    }
    __syncthreads();
  }
#pragma unroll
  for (int m = 0; m < 4; ++m) {
    long r0 = m0 + wr * 64 + m * 16 + lg * 4;
#pragma unroll
    for (int n = 0; n < 4; ++n) {
      long c = n0 + wc * 64 + n * 16 + l15;
      float bv = bias ? bias[c] : 0.f;
#pragma unroll
      for (int j = 0; j < 4; ++j) {
        float v = acc[m][n][j] + bv;
        if (WRITE_BF16)
          ((unsigned short*)Cout)[(r0 + j) * (long)N + c] = f2bf(v);
        else
          ((float*)Cout)[(r0 + j) * (long)N + c] = v;
      }
    }
  }
}

// ---------------- stage 2: l2norm Q/K, tgt = LN(V-K) part, eta ----------------
__global__ __launch_bounds__(256) void stage2(
    const unsigned short* __restrict__ QKVL, const float* __restrict__ tnw,
    const float* __restrict__ tnb, unsigned short* __restrict__ XQn,
    unsigned short* __restrict__ XKn, unsigned short* __restrict__ TGT,
    float* __restrict__ eta_buf) {
  int wid = threadIdx.x >> 6, lane = threadIdx.x & 63;
  long idx = (long)blockIdx.x * 4 + wid;
  long t = idx >> 4;
  int h = (int)(idx & 15);
  size_t base = (size_t)t * 3200;
  float q = bf2f(QKVL[base + h * 64 + lane]);
  float k = bf2f(QKVL[base + 1024 + h * 64 + lane]);
  float v = bf2f(QKVL[base + 2048 + h * 64 + lane]);
  float sq = q * q, sk = k * k;
#pragma unroll
  for (int o = 1; o < 64; o <<= 1) {
    sq += __shfl_xor(sq, o);
    sk += __shfl_xor(sk, o);
  }
  float qn = q / fmaxf(sqrtf(sq), 1e-12f);
  float kn = k / fmaxf(sqrtf(sk), 1e-12f);
  float d = v - kn;
  float s1 = d, s2 = d * d;
#pragma unroll
  for (int o = 1; o < 64; o <<= 1) {
    s1 += __shfl_xor(s1, o);
    s2 += __shfl_xor(s2, o);
  }
  float mu = s1 * 0.015625f;
  float var1 = fmaxf(s2 - 64.f * mu * mu, 0.f) * (1.f / 63.f);  // ddof=1
  float sd = sqrtf(var1);
  float tgt = tnw[h * 64 + lane] * ((d - mu) / (sd + 1e-5f)) + tnb[h * 64 + lane];
  size_t ob = (size_t)t * 1024 + h * 64 + lane;
  XQn[ob] = f2bf(qn);
  XKn[ob] = f2bf(kn);
  TGT[ob] = f2bf(tgt);
  if (lane == 0) {
    float logit = bf2f(QKVL[base + 3072 + h]);
    float sig = 1.f / (1.f + expf(-logit));
    long bb = t >> 13, l = t & 8191;
    eta_buf[(size_t)(bb * 16 + h) * 8192 + l] = sig * (1.f / 4096.f);
  }
}

// ---------------- stage 3: sequential TTT scan ----------------
// One block per (b,h) chain: 8 waves, role-split, 2 raw barriers per chunk.
//   A (waves 0-3): Z1, LN-bwd -> gradT | Z1_bar, LN-fwd -> y
//   B (waves 4-7): xkTe, Attn, Gc      | W-update -> WT, bpart
// Input staging double-buffered; b-state in A registers; no vmcnt drains.
__global__ __launch_bounds__(512, 1) void ttt_scan(
    const unsigned short* __restrict__ XQ, const unsigned short* __restrict__ XK,
    const unsigned short* __restrict__ TG, const float* __restrict__ eta_buf,
    const float* __restrict__ W1, const float* __restrict__ b1,
    const float* __restrict__ tnw, const float* __restrict__ tnb,
    float* __restrict__ y) {
  const int bh = blockIdx.x;
  const int b = bh >> 4, h = bh & 15;
  const int tid = threadIdx.x;
  const int lane = tid & 63, wid = tid >> 6;  // wid 0..7
  const bool isA = wid < 4;
  const int q = wid & 3;
  const int l15 = lane & 15, lg = lane >> 4;

  __shared__ __align__(16) unsigned short xq_s[2][64 * 72];
  __shared__ __align__(16) unsigned short tg_s[2][64 * 72];
  __shared__ __align__(16) unsigned short xk_s[2][64 * 72];
  __shared__ __align__(16) unsigned short gc_s[64 * 72];
  __shared__ __align__(16) unsigned short gradT[64 * 72];
  __shared__ __align__(16) unsigned short xkTe[64 * 72];
  __shared__ __align__(16) unsigned short WT_b[2][64 * 72];
  __shared__ float eta_s[2][64];
  __shared__ float bpart[4][64];

  const size_t tokb = (size_t)b * 8192;
  const int col0 = h * 64;
  const int rr_ = q * 16 + (lane >> 3);  // +j*8
  const int c8_ = (lane & 7) * 8;

  short8 pA0[2], pA1[2], pB0[2];
  float peta = 0.f;
  float bstv[4], gwv[4], gbv[4];
  f32x4 Wreg[4];

  // ---- prologue ----
  if (isA) {
#pragma unroll
    for (int n = 0; n < 4; ++n) {
      int e = n * 16 + l15;
      bstv[n] = b1[h * 64 + e];
      gwv[n] = tnw[h * 64 + e];
      gbv[n] = tnb[h * 64 + e];
    }
#pragma unroll
    for (int j = 0; j < 2; ++j) {
      size_t g = (tokb + rr_ + j * 8) * 1024 + col0 + c8_;
      pA0[j] = *(const short8*)&XQ[g];
      pA1[j] = *(const short8*)&TG[g];
    }
#pragma unroll
    for (int j = 0; j < 2; ++j) {
      int rr = rr_ + j * 8;
      *(short8*)&xq_s[0][rr * 72 + c8_] = pA0[j];
      *(short8*)&tg_s[0][rr * 72 + c8_] = pA1[j];
    }
#pragma unroll
    for (int j = 0; j < 2; ++j) {
      size_t g = (tokb + 64 + rr_ + j * 8) * 1024 + col0 + c8_;
      pA0[j] = *(const short8*)&XQ[g];
      pA1[j] = *(const short8*)&TG[g];
    }
  } else {
#pragma unroll
    for (int j = 0; j < 2; ++j)
      pB0[j] = *(const short8*)&XK[(tokb + rr_ + j * 8) * 1024 + col0 + c8_];
#pragma unroll
    for (int j = 0; j < 2; ++j)
      *(short8*)&xk_s[0][(rr_ + j * 8) * 72 + c8_] = pB0[j];
#pragma unroll
    for (int j = 0; j < 2; ++j)
      pB0[j] = *(const short8*)&XK[(tokb + 64 + rr_ + j * 8) * 1024 + col0 + c8_];
#pragma unroll
    for (int n = 0; n < 4; ++n)
#pragma unroll
      for (int jj = 0; jj < 4; ++jj) {
        int d = q * 16 + lg * 4 + jj, e = n * 16 + l15;
        float w = W1[h * 4096 + d * 64 + e];
        Wreg[n][jj] = w;
        WT_b[0][e * 72 + d] = f2bf(w);
      }
    if (wid == 4) {
      eta_s[0][lane] = eta_buf[(size_t)bh * 8192 + lane];
      peta = eta_buf[(size_t)bh * 8192 + 64 + lane];
    }
  }
  __syncthreads();

  for (int nc = 0; nc < 128; ++nc) {
    const int p = nc & 1;
    const unsigned short* WTc = WT_b[p];
    unsigned short* WTn = WT_b[p ^ 1];

    // ================= phase 1 =================
    if (isA) {
      if (nc) {
#pragma unroll
        for (int n = 0; n < 4; ++n) {
          int e = n * 16 + l15;
          bstv[n] -= bpart[0][e] + bpart[1][e] + bpart[2][e] + bpart[3][e];
        }
      }
      if (nc + 1 < 128) {
#pragma unroll
        for (int j = 0; j < 2; ++j) {
          int rr = rr_ + j * 8;
          *(short8*)&xq_s[p ^ 1][rr * 72 + c8_] = pA0[j];
          *(short8*)&tg_s[p ^ 1][rr * 72 + c8_] = pA1[j];
        }
      }
      if (nc + 2 < 128) {
#pragma unroll
        for (int j = 0; j < 2; ++j) {
          size_t g = (tokb + (nc + 2) * 64 + rr_ + j * 8) * 1024 + col0 + c8_;
          pA0[j] = *(const short8*)&XQ[g];
          pA1[j] = *(const short8*)&TG[g];
        }
      }
      f32x4 accZ[4];
#pragma unroll
      for (int n = 0; n < 4; ++n)
        accZ[n] = (f32x4){bstv[n], bstv[n], bstv[n], bstv[n]};
      __builtin_amdgcn_s_setprio(1);
#pragma unroll
      for (int kk = 0; kk < 2; ++kk) {
        const int ko = kk * 32 + lg * 8;
        short8 a_xk = *(const short8*)&xk_s[p][(q * 16 + l15) * 72 + ko];
#pragma unroll
        for (int n = 0; n < 4; ++n) {
          short8 b_w = *(const short8*)&WTc[(n * 16 + l15) * 72 + ko];
          accZ[n] = __builtin_amdgcn_mfma_f32_16x16x32_bf16(a_xk, b_w, accZ[n], 0, 0, 0);
        }
      }
      __builtin_amdgcn_s_setprio(0);
      float grv[4][4];
#pragma unroll
      for (int j = 0; j < 4; ++j) {
        const int r = q * 16 + lg * 4 + j;
        float z[4], s1 = 0.f, s2 = 0.f;
#pragma unroll
        for (int n = 0; n < 4; ++n) {
          z[n] = accZ[n][j];
          s1 += z[n];
          s2 += z[n] * z[n];
        }
        s1 = dpp16_sum(s1);
        s2 = dpp16_sum(s2);
        float mu = s1 * 0.015625f;
        float var = s2 * 0.015625f - mu * mu;
        float rstd = rsqrtf(var + 1e-6f);
        float xh[4], gx[4], s3 = 0.f, s4 = 0.f;
#pragma unroll
        for (int n = 0; n < 4; ++n) {
          xh[n] = (z[n] - mu) * rstd;
          float tg = bf2f(tg_s[p][r * 72 + n * 16 + l15]);
          float go = gwv[n] * xh[n] + gbv[n] - tg;
          gx[n] = go * gwv[n];
          s3 += gx[n];
          s4 += gx[n] * xh[n];
        }
        s3 = dpp16_sum(s3);
        s4 = dpp16_sum(s4);
#pragma unroll
        for (int n = 0; n < 4; ++n)
          grv[n][j] = (64.f * gx[n] - s3 - xh[n] * s4) * rstd * 0.015625f;
      }
#pragma unroll
      for (int n = 0; n < 4; ++n) {
        us4 pk = {f2bf(grv[n][0]), f2bf(grv[n][1]), f2bf(grv[n][2]),
                  f2bf(grv[n][3])};
        *(us4*)&gradT[(n * 16 + l15) * 72 + q * 16 + lg * 4] = pk;
      }
    } else {
      if (nc + 1 < 128) {
#pragma unroll
        for (int j = 0; j < 2; ++j)
          *(short8*)&xk_s[p ^ 1][(rr_ + j * 8) * 72 + c8_] = pB0[j];
        if (wid == 4) eta_s[p ^ 1][lane] = peta;
      }
      if (nc + 2 < 128) {
#pragma unroll
        for (int j = 0; j < 2; ++j)
          pB0[j] = *(const short8*)
              &XK[(tokb + (nc + 2) * 64 + rr_ + j * 8) * 1024 + col0 + c8_];
        if (wid == 4) peta = eta_buf[(size_t)bh * 8192 + (nc + 2) * 64 + lane];
      }
      // xkTe[d][c] = -eta[c]*xk[c][d], b64-packed writes
#pragma unroll
      for (int it = 0; it < 4; ++it) {
        int c0 = q * 16 + it * 4;
        us4 pk;
#pragma unroll
        for (int u = 0; u < 4; ++u)
          pk[u] = f2bf(-eta_s[p][c0 + u] * bf2f(xk_s[p][(c0 + u) * 72 + lane]));
        *(us4*)&xkTe[lane * 72 + c0] = pk;
      }
      f32x4 accA[4];
#pragma unroll
      for (int n = 0; n < 4; ++n) accA[n] = (f32x4){0.f, 0.f, 0.f, 0.f};
      __builtin_amdgcn_s_setprio(1);
#pragma unroll
      for (int kk = 0; kk < 2; ++kk) {
        const int ko = kk * 32 + lg * 8;
        short8 a_xq = *(const short8*)&xq_s[p][(q * 16 + l15) * 72 + ko];
#pragma unroll
        for (int n = 0; n < 4; ++n) {
          short8 b_k = *(const short8*)&xk_s[p][(n * 16 + l15) * 72 + ko];
          accA[n] = __builtin_amdgcn_mfma_f32_16x16x32_bf16(a_xq, b_k, accA[n], 0, 0, 0);
        }
      }
      __builtin_amdgcn_s_setprio(0);
#pragma unroll
      for (int j = 0; j < 4; ++j) {
        const int r = q * 16 + lg * 4 + j;
#pragma unroll
        for (int n = 0; n < 4; ++n) {
          int cj = n * 16 + l15;
          float v = (cj <= r) ? (-eta_s[p][cj] * (1.f + accA[n][j])) : 0.f;
          gc_s[r * 72 + cj] = f2bf(v);
        }
      }
    }
    barrier_fast();  // X

    // ================= phase 2 =================
    if (isA) {
      f32x4 accZb[4];
#pragma unroll
      for (int n = 0; n < 4; ++n)
        accZb[n] = (f32x4){bstv[n], bstv[n], bstv[n], bstv[n]};
      __builtin_amdgcn_s_setprio(1);
#pragma unroll
      for (int kk = 0; kk < 2; ++kk) {
        const int ko = kk * 32 + lg * 8;
        short8 a_xq = *(const short8*)&xq_s[p][(q * 16 + l15) * 72 + ko];
        short8 a_gc = *(const short8*)&gc_s[(q * 16 + l15) * 72 + ko];
#pragma unroll
        for (int n = 0; n < 4; ++n) {
          short8 b_w = *(const short8*)&WTc[(n * 16 + l15) * 72 + ko];
          short8 b_g = *(const short8*)&gradT[(n * 16 + l15) * 72 + ko];
          accZb[n] = __builtin_amdgcn_mfma_f32_16x16x32_bf16(a_xq, b_w, accZb[n], 0, 0, 0);
          accZb[n] = __builtin_amdgcn_mfma_f32_16x16x32_bf16(a_gc, b_g, accZb[n], 0, 0, 0);
        }
      }
      __builtin_amdgcn_s_setprio(0);
#pragma unroll
      for (int j = 0; j < 4; ++j) {
        const int r = q * 16 + lg * 4 + j;
        float z[4], s1 = 0.f, s2 = 0.f;
#pragma unroll
        for (int n = 0; n < 4; ++n) {
          z[n] = accZb[n][j];
          s1 += z[n];
          s2 += z[n] * z[n];
        }
        s1 = dpp16_sum(s1);
        s2 = dpp16_sum(s2);
        float mu = s1 * 0.015625f;
        float var = s2 * 0.015625f - mu * mu;
        float rstd = rsqrtf(var + 1e-6f);
        size_t gbase = (tokb + nc * 64 + r) * 1024 + col0;
#pragma unroll
        for (int n = 0; n < 4; ++n) {
          int e = n * 16 + l15;
          float ov = bf2f(xq_s[p][r * 72 + e]) + gwv[n] * ((z[n] - mu) * rstd) + gbv[n];
          y[gbase + e] = ov;
        }
      }
    } else {
      f32x4 accW[4];
#pragma unroll
      for (int n = 0; n < 4; ++n) accW[n] = Wreg[n];
      __builtin_amdgcn_s_setprio(1);
#pragma unroll
      for (int kk = 0; kk < 2; ++kk) {
        const int ko = kk * 32 + lg * 8;
        short8 a_ke = *(const short8*)&xkTe[(q * 16 + l15) * 72 + ko];
#pragma unroll
        for (int n = 0; n < 4; ++n) {
          short8 b_g = *(const short8*)&gradT[(n * 16 + l15) * 72 + ko];
          accW[n] = __builtin_amdgcn_mfma_f32_16x16x32_bf16(a_ke, b_g, accW[n], 0, 0, 0);
        }
      }
      __builtin_amdgcn_s_setprio(0);
#pragma unroll
      for (int n = 0; n < 4; ++n) {
        Wreg[n] = accW[n];
        us4 pk = {f2bf(accW[n][0]), f2bf(accW[n][1]), f2bf(accW[n][2]),
                  f2bf(accW[n][3])};
        *(us4*)&WTn[(n * 16 + l15) * 72 + q * 16 + lg * 4] = pk;
      }
      {
        float s = 0.f;
#pragma unroll
        for (int it = 0; it < 4; ++it) {
          us4 gv = *(const us4*)&gradT[lane * 72 + q * 16 + it * 4];
#pragma unroll
          for (int u = 0; u < 4; ++u)
            s += eta_s[p][q * 16 + it * 4 + u] * bf2f(gv[u]);
        }
        bpart[q][lane] = s;
      }
    }
    barrier_fast();  // Y
  }
}

// ---------------- stage 4: post layernorm over D=1024 ----------------
__global__ __launch_bounds__(256) void postnorm(
    const float* __restrict__ yv, const float* __restrict__ pw,
    const float* __restrict__ pb, unsigned short* __restrict__ yn) {
  int t = blockIdx.x;
  int tid = threadIdx.x, lane = tid & 63, wid = tid >> 6;
  const float* row = yv + (size_t)t * 1024;
  float4 v = *(const float4*)&row[tid * 4];
  float s1 = v.x + v.y + v.z + v.w;
  float s2 = v.x * v.x + v.y * v.y + v.z * v.z + v.w * v.w;
#pragma unroll
  for (int o = 1; o < 64; o <<= 1) {
    s1 += __shfl_xor(s1, o);
    s2 += __shfl_xor(s2, o);
  }
  __shared__ float r1[4], r2[4];
  if (lane == 0) {
    r1[wid] = s1;
    r2[wid] = s2;
  }
  __syncthreads();
  s1 = r1[0] + r1[1] + r1[2] + r1[3];
  s2 = r2[0] + r2[1] + r2[2] + r2[3];
  float mu = s1 * (1.f / 1024.f);
  float var = s2 * (1.f / 1024.f) - mu * mu;
  float rstd = rsqrtf(var + 1e-6f);
  int c = tid * 4;
  us4 o4 = {f2bf(pw[c] * ((v.x - mu) * rstd) + pb[c]),
            f2bf(pw[c + 1] * ((v.y - mu) * rstd) + pb[c + 1]),
            f2bf(pw[c + 2] * ((v.z - mu) * rstd) + pb[c + 2]),
            f2bf(pw[c + 3] * ((v.w - mu) * rstd) + pb[c + 3])};
  *(us4*)&yn[(size_t)t * 1024 + c] = o4;
}

// ---------------------------------------------------------------------------
extern "C" void kernel_launch(void* const* d_in, const int* in_sizes, int n_in,
                              void* d_out, int out_size, void* d_ws,
                              size_t ws_size, hipStream_t stream) {
  const float* hs  = (const float*)d_in[0];
  const float* wqw = (const float*)d_in[1];
  const float* wqb = (const float*)d_in[2];
  const float* wkw = (const float*)d_in[3];
  const float* wkb = (const float*)d_in[4];
  const float* wvw = (const float*)d_in[5];
  const float* wvb = (const float*)d_in[6];
  const float* wow = (const float*)d_in[7];
  const float* wob = (const float*)d_in[8];
  const float* tnw = (const float*)d_in[9];
  const float* tnb = (const float*)d_in[10];
  const float* lrw = (const float*)d_in[11];
  const float* lrb = (const float*)d_in[12];
  const float* W1  = (const float*)d_in[13];
  const float* b1  = (const float*)d_in[14];
  const float* pnw = (const float*)d_in[15];
  const float* pnb = (const float*)d_in[16];

  const size_t OFF_WCAT  = 67108864;
  const size_t OFF_BIASC = OFF_WCAT + 6553600;
  const size_t OFF_WOBF  = OFF_BIASC + 12800;
  const size_t OFF_QKVL  = OFF_WOBF + 2097152;
  const size_t OFF_XQ    = OFF_QKVL + 209715200;
  const size_t OFF_XK    = OFF_XQ + 67108864;
  const size_t OFF_XV    = OFF_XK + 67108864;
  const size_t OFF_ETA   = OFF_XV + 67108864;
  const size_t NEEDED    = OFF_ETA + 2097152;
  if (ws_size < NEEDED) return;

  char* ws = (char*)d_ws;
  unsigned short* hs_bf = (unsigned short*)ws;
  unsigned short* Wcat  = (unsigned short*)(ws + OFF_WCAT);
  float* biasc          = (float*)(ws + OFF_BIASC);
  unsigned short* wo_bf = (unsigned short*)(ws + OFF_WOBF);
  unsigned short* QKVL  = (unsigned short*)(ws + OFF_QKVL);
  float* yv             = (float*)(ws + OFF_QKVL);
  unsigned short* ynorm = (unsigned short*)(ws + OFF_QKVL + 134217728);
  unsigned short* XQn   = (unsigned short*)(ws + OFF_XQ);
  unsigned short* XKn   = (unsigned short*)(ws + OFF_XK);
  unsigned short* TGT   = (unsigned short*)(ws + OFF_XV);
  float* eta_buf        = (float*)(ws + OFF_ETA);

  cvt_f32_bf16<<<32768, 256, 0, stream>>>(hs, hs_bf, 33554432L);
  build_wcat<<<12800, 256, 0, stream>>>(wqw, wkw, wvw, lrw, wqb, wkb, wvb, lrb,
                                        Wcat, biasc);
  cvt_f32_bf16<<<1024, 256, 0, stream>>>(wow, wo_bf, 1048576L);
  gemm_bt<1><<<dim3(25, 256), 256, 0, stream>>>(hs_bf, Wcat, biasc, QKVL,
                                                32768, 3200, 1024);
  stage2<<<131072, 256, 0, stream>>>(QKVL, tnw, tnb, XQn, XKn, TGT, eta_buf);
  ttt_scan<<<64, 512, 0, stream>>>(XQn, XKn, TGT, eta_buf, W1, b1, tnw, tnb, yv);
  postnorm<<<32768, 256, 0, stream>>>(yv, pnw, pnb, ynorm);
  gemm_bt<0><<<dim3(8, 256), 256, 0, stream>>>(ynorm, wo_bf, wob, d_out,
                                               32768, 1024, 1024);
}

// Round 4
// 956.158 us; speedup vs baseline: 1.5768x; 1.1617x over previous
//
#include <hip/hip_runtime.h>

// ---------------------------------------------------------------------------
// TTT layer forward: B=4, L=8192, D=1024, H=16, HD=64, C=64, NC=128
// ---------------------------------------------------------------------------

typedef __attribute__((ext_vector_type(8))) short short8;
typedef __attribute__((ext_vector_type(4))) float f32x4;
typedef __attribute__((ext_vector_type(4))) unsigned short us4;

__device__ __forceinline__ float bf2f(unsigned short s) {
  union { unsigned int u; float f; } c;
  c.u = ((unsigned int)s) << 16;
  return c.f;
}
__device__ __forceinline__ unsigned short f2bf(float f) {
  union { float f; unsigned int u; } c;
  c.f = f;
  unsigned int u = c.u;
  return (unsigned short)((u + 0x7FFFu + ((u >> 16) & 1u)) >> 16);
}

__device__ __forceinline__ void gload_lds16(const void* g, void* l) {
  __builtin_amdgcn_global_load_lds(
      (const __attribute__((address_space(1))) unsigned int*)g,
      (__attribute__((address_space(3))) unsigned int*)l, 16, 0, 0);
}

__device__ __forceinline__ float dpp16_sum(float x) {
  int v = __float_as_int(x);
  x += __int_as_float(__builtin_amdgcn_update_dpp(v, v, 0xB1, 0xF, 0xF, true));
  v = __float_as_int(x);
  x += __int_as_float(__builtin_amdgcn_update_dpp(v, v, 0x4E, 0xF, 0xF, true));
  v = __float_as_int(x);
  x += __int_as_float(__builtin_amdgcn_update_dpp(v, v, 0x141, 0xF, 0xF, true));
  v = __float_as_int(x);
  x += __int_as_float(__builtin_amdgcn_update_dpp(v, v, 0x140, 0xF, 0xF, true));
  return x;
}

// raw barrier: no vmcnt drain
__device__ __forceinline__ void barrier_fast() {
  __builtin_amdgcn_sched_barrier(0);
  asm volatile("s_waitcnt lgkmcnt(0)" ::: "memory");
  __builtin_amdgcn_s_barrier();
  asm volatile("" ::: "memory");
  __builtin_amdgcn_sched_barrier(0);
}
__device__ __forceinline__ void bar_nowait() {
  __builtin_amdgcn_sched_barrier(0);
  asm volatile("" ::: "memory");
  __builtin_amdgcn_s_barrier();
  asm volatile("" ::: "memory");
  __builtin_amdgcn_sched_barrier(0);
}

// ---------------- conversion kernels ----------------
__global__ __launch_bounds__(256) void cvt_f32_bf16(
    const float* __restrict__ in, unsigned short* __restrict__ out, long n) {
  long i = ((long)blockIdx.x * 256 + threadIdx.x) * 4;
  if (i + 3 < n) {
    float4 v = *(const float4*)&in[i];
    us4 o = { f2bf(v.x), f2bf(v.y), f2bf(v.z), f2bf(v.w) };
    *(us4*)&out[i] = o;
  }
}

// Wcat rows: [0,1024)=wq, [1024,2048)=wk, [2048,3072)=wv, [3072,3088)=lr_w,
// rows [3088,3328) zero-padded so N tiles divide 256.
__global__ __launch_bounds__(256) void build_wcat(
    const float* __restrict__ wq, const float* __restrict__ wk,
    const float* __restrict__ wv, const float* __restrict__ lrw,
    const float* __restrict__ wqb, const float* __restrict__ wkb,
    const float* __restrict__ wvb, const float* __restrict__ lrb,
    unsigned short* __restrict__ Wcat, float* __restrict__ biasc) {
  int i = blockIdx.x * 256 + threadIdx.x;  // 0 .. 3328*1024-1
  int row = i >> 10, col = i & 1023;
  float v;
  if (row < 1024)      v = wq[i];
  else if (row < 2048) v = wk[i - 1048576];
  else if (row < 3072) v = wv[i - 2097152];
  else if (row < 3088) v = lrw[(row - 3072) * 1024 + col];
  else                 v = 0.f;
  Wcat[i] = f2bf(v);
  if (i < 3328) {
    float bv;
    if (i < 1024)      bv = wqb[i];
    else if (i < 2048) bv = wkb[i - 1024];
    else if (i < 3072) bv = wvb[i - 2048];
    else if (i < 3088) bv = lrb[i - 3072];
    else               bv = 0.f;
    biasc[i] = bv;
  }
}

// ---------------- 256x256 8-wave GEMM: C = A[M,K] @ B[N,K]^T + bias ----------
// BK=32, 4 LDS buffers (A 4x16KB + B 4x16KB = 128KB). Stage tile t+3 while
// computing tile t (stage target never aliases a read buffer). One counted
// vmcnt(8) per K-tile (never 0). XOR-swizzled LDS, raw barriers, setprio.
template <int WRITE_BF16>
__global__ __launch_bounds__(512, 1) void gemm256(
    const unsigned short* __restrict__ A, const unsigned short* __restrict__ B,
    const float* __restrict__ bias, void* __restrict__ Cout,
    long M, long N, long K, int NTILN, long ldc) {
  __shared__ __align__(16) unsigned short g_lds[65536];  // 128 KB
  char* ldsc = (char*)g_lds;
  const int tid = threadIdx.x, lane = tid & 63, wid = tid >> 6;
  const int wm = wid >> 2, wn = wid & 3;
  const int l15 = lane & 15, lg = lane >> 4;

  // XCD swizzle + M-major raster (nwg % 8 == 0 by construction)
  unsigned nwg = gridDim.x, bid = blockIdx.x;
  unsigned cpx = nwg >> 3;
  unsigned swz = (bid & 7) * cpx + (bid >> 3);
  unsigned nidx = swz % (unsigned)NTILN, midx = swz / (unsigned)NTILN;
  const long m0 = (long)midx * 256, n0 = (long)nidx * 256;
  const long ldab = K * 2;  // row bytes of A and B

  // staging constants: half-tile = 128 rows x 64B; 1 load/thread/half
  const int srow = wid * 16 + (lane >> 2);                       // row in half
  const int scol = ((lane & 3) * 16) ^ (((lane >> 3) & 3) << 4); // swz source
  const int sdst = wid * 1024;                                   // uniform dst
  const char* Ab = (const char*)A;
  const char* Bb = (const char*)B;

  // read constants: frag = 16B at (row*64) ^ swizzle, row = base + l15
  const int acol = (lg * 16) ^ (((l15 >> 1) & 3) << 4);
  const int aro = (wm * 128 + l15) * 64 + acol;           // + buf*16K + i*1K
  const int bro = 65536 + (wn * 64 + l15) * 64 + acol;    // + buf*16K + nf*1K

#define STG_A(tt, h, bb)                                                     \
  gload_lds16(Ab + (size_t)(m0 + (h) * 128 + srow) * ldab + (size_t)(tt) * 64 \
                  + scol,                                                     \
              ldsc + (bb) * 16384 + (h) * 8192 + sdst)
#define STG_B(tt, h, bb)                                                     \
  gload_lds16(Bb + (size_t)(n0 + (h) * 128 + srow) * ldab + (size_t)(tt) * 64 \
                  + scol,                                                     \
              ldsc + 65536 + (bb) * 16384 + (h) * 8192 + sdst)

  f32x4 acc[8][4];
#pragma unroll
  for (int m = 0; m < 8; ++m)
#pragma unroll
    for (int n = 0; n < 4; ++n) acc[m][n] = (f32x4){0.f, 0.f, 0.f, 0.f};

  const int NT = (int)(K >> 5);  // K-tiles of 32

  // prologue: stage tiles 0,1,2; wait tile0 (8 = 2 tiles outstanding)
#pragma unroll
  for (int tt = 0; tt < 3; ++tt) {
    STG_A(tt, 0, tt); STG_A(tt, 1, tt);
    STG_B(tt, 0, tt); STG_B(tt, 1, tt);
  }
  asm volatile("s_waitcnt vmcnt(8)" ::: "memory");
  bar_nowait();

#pragma unroll 1
  for (int t = 0; t < NT; ++t) {
    const int buf = t & 3, sb = (t + 3) & 3;
    const bool doStage = (t + 3 < NT);
    const char* ab = ldsc + buf * 16384 + aro;
    const char* bb = ldsc + buf * 16384 + bro;

    // ---- phase 1: m-low quadrant ----
    short8 av[4], bv[4];
#pragma unroll
    for (int i = 0; i < 4; ++i) av[i] = *(const short8*)(ab + i * 1024);
#pragma unroll
    for (int nf = 0; nf < 4; ++nf) bv[nf] = *(const short8*)(bb + nf * 1024);
    if (doStage) { STG_A(t + 3, 0, sb); STG_A(t + 3, 1, sb); }
    bar_nowait();
    __builtin_amdgcn_s_setprio(1);
#pragma unroll
    for (int i = 0; i < 4; ++i)
#pragma unroll
      for (int nf = 0; nf < 4; ++nf)
        acc[i][nf] = __builtin_amdgcn_mfma_f32_16x16x32_bf16(av[i], bv[nf],
                                                             acc[i][nf], 0, 0, 0);
    __builtin_amdgcn_s_setprio(0);
    bar_nowait();

    // ---- phase 2: m-high quadrant ----
#pragma unroll
    for (int i = 0; i < 4; ++i) av[i] = *(const short8*)(ab + 4096 + i * 1024);
    if (doStage) { STG_B(t + 3, 0, sb); STG_B(t + 3, 1, sb); }
    bar_nowait();
    __builtin_amdgcn_s_setprio(1);
#pragma unroll
    for (int i = 0; i < 4; ++i)
#pragma unroll
      for (int nf = 0; nf < 4; ++nf)
        acc[4 + i][nf] = __builtin_amdgcn_mfma_f32_16x16x32_bf16(
            av[i], bv[nf], acc[4 + i][nf], 0, 0, 0);
    __builtin_amdgcn_s_setprio(0);
    asm volatile("s_waitcnt vmcnt(8)" ::: "memory");  // tile t+1 landed
    bar_nowait();
  }
#undef STG_A
#undef STG_B

  // epilogue
#pragma unroll
  for (int mf = 0; mf < 8; ++mf) {
    long r0 = m0 + wm * 128 + mf * 16 + lg * 4;
#pragma unroll
    for (int nf = 0; nf < 4; ++nf) {
      long c = n0 + wn * 64 + nf * 16 + l15;
      float bvv = bias ? bias[c] : 0.f;
#pragma unroll
      for (int j = 0; j < 4; ++j) {
        float v = acc[mf][nf][j] + bvv;
        if (WRITE_BF16)
          ((unsigned short*)Cout)[(r0 + j) * ldc + c] = f2bf(v);
        else
          ((float*)Cout)[(r0 + j) * ldc + c] = v;
      }
    }
  }
}

// ---------------- stage 2: l2norm Q/K, tgt = LN(V-K) part, eta ----------------
__global__ __launch_bounds__(256) void stage2(
    const unsigned short* __restrict__ QKVL, const float* __restrict__ tnw,
    const float* __restrict__ tnb, unsigned short* __restrict__ XQn,
    unsigned short* __restrict__ XKn, unsigned short* __restrict__ TGT,
    float* __restrict__ eta_buf) {
  int wid = threadIdx.x >> 6, lane = threadIdx.x & 63;
  long idx = (long)blockIdx.x * 4 + wid;
  long t = idx >> 4;
  int h = (int)(idx & 15);
  size_t base = (size_t)t * 3328;
  float q = bf2f(QKVL[base + h * 64 + lane]);
  float k = bf2f(QKVL[base + 1024 + h * 64 + lane]);
  float v = bf2f(QKVL[base + 2048 + h * 64 + lane]);
  float sq = q * q, sk = k * k;
#pragma unroll
  for (int o = 1; o < 64; o <<= 1) {
    sq += __shfl_xor(sq, o);
    sk += __shfl_xor(sk, o);
  }
  float qn = q / fmaxf(sqrtf(sq), 1e-12f);
  float kn = k / fmaxf(sqrtf(sk), 1e-12f);
  float d = v - kn;
  float s1 = d, s2 = d * d;
#pragma unroll
  for (int o = 1; o < 64; o <<= 1) {
    s1 += __shfl_xor(s1, o);
    s2 += __shfl_xor(s2, o);
  }
  float mu = s1 * 0.015625f;
  float var1 = fmaxf(s2 - 64.f * mu * mu, 0.f) * (1.f / 63.f);  // ddof=1
  float sd = sqrtf(var1);
  float tgt = tnw[h * 64 + lane] * ((d - mu) / (sd + 1e-5f)) + tnb[h * 64 + lane];
  size_t ob = (size_t)t * 1024 + h * 64 + lane;
  XQn[ob] = f2bf(qn);
  XKn[ob] = f2bf(kn);
  TGT[ob] = f2bf(tgt);
  if (lane == 0) {
    float logit = bf2f(QKVL[base + 3072 + h]);
    float sig = 1.f / (1.f + expf(-logit));
    long bb = t >> 13, l = t & 8191;
    eta_buf[(size_t)(bb * 16 + h) * 8192 + l] = sig * (1.f / 4096.f);
  }
}

// ---------------- stage 3: sequential TTT scan ----------------
__global__ __launch_bounds__(512, 1) void ttt_scan(
    const unsigned short* __restrict__ XQ, const unsigned short* __restrict__ XK,
    const unsigned short* __restrict__ TG, const float* __restrict__ eta_buf,
    const float* __restrict__ W1, const float* __restrict__ b1,
    const float* __restrict__ tnw, const float* __restrict__ tnb,
    float* __restrict__ y) {
  const int bh = blockIdx.x;
  const int b = bh >> 4, h = bh & 15;
  const int tid = threadIdx.x;
  const int lane = tid & 63, wid = tid >> 6;
  const bool isA = wid < 4;
  const int q = wid & 3;
  const int l15 = lane & 15, lg = lane >> 4;

  __shared__ __align__(16) unsigned short xq_s[2][64 * 72];
  __shared__ __align__(16) unsigned short tg_s[2][64 * 72];
  __shared__ __align__(16) unsigned short xk_s[2][64 * 72];
  __shared__ __align__(16) unsigned short gc_s[64 * 72];
  __shared__ __align__(16) unsigned short gradT[64 * 72];
  __shared__ __align__(16) unsigned short xkTe[64 * 72];
  __shared__ __align__(16) unsigned short WT_b[2][64 * 72];
  __shared__ float eta_s[2][64];
  __shared__ float bpart[4][64];

  const size_t tokb = (size_t)b * 8192;
  const int col0 = h * 64;
  const int rr_ = q * 16 + (lane >> 3);
  const int c8_ = (lane & 7) * 8;

  short8 pA0[2], pA1[2], pB0[2];
  float peta = 0.f;
  float bstv[4], gwv[4], gbv[4];
  f32x4 Wreg[4];

  if (isA) {
#pragma unroll
    for (int n = 0; n < 4; ++n) {
      int e = n * 16 + l15;
      bstv[n] = b1[h * 64 + e];
      gwv[n] = tnw[h * 64 + e];
      gbv[n] = tnb[h * 64 + e];
    }
#pragma unroll
    for (int j = 0; j < 2; ++j) {
      size_t g = (tokb + rr_ + j * 8) * 1024 + col0 + c8_;
      pA0[j] = *(const short8*)&XQ[g];
      pA1[j] = *(const short8*)&TG[g];
    }
#pragma unroll
    for (int j = 0; j < 2; ++j) {
      int rr = rr_ + j * 8;
      *(short8*)&xq_s[0][rr * 72 + c8_] = pA0[j];
      *(short8*)&tg_s[0][rr * 72 + c8_] = pA1[j];
    }
#pragma unroll
    for (int j = 0; j < 2; ++j) {
      size_t g = (tokb + 64 + rr_ + j * 8) * 1024 + col0 + c8_;
      pA0[j] = *(const short8*)&XQ[g];
      pA1[j] = *(const short8*)&TG[g];
    }
  } else {
#pragma unroll
    for (int j = 0; j < 2; ++j)
      pB0[j] = *(const short8*)&XK[(tokb + rr_ + j * 8) * 1024 + col0 + c8_];
#pragma unroll
    for (int j = 0; j < 2; ++j)
      *(short8*)&xk_s[0][(rr_ + j * 8) * 72 + c8_] = pB0[j];
#pragma unroll
    for (int j = 0; j < 2; ++j)
      pB0[j] = *(const short8*)&XK[(tokb + 64 + rr_ + j * 8) * 1024 + col0 + c8_];
#pragma unroll
    for (int n = 0; n < 4; ++n)
#pragma unroll
      for (int jj = 0; jj < 4; ++jj) {
        int d = q * 16 + lg * 4 + jj, e = n * 16 + l15;
        float w = W1[h * 4096 + d * 64 + e];
        Wreg[n][jj] = w;
        WT_b[0][e * 72 + d] = f2bf(w);
      }
    if (wid == 4) {
      eta_s[0][lane] = eta_buf[(size_t)bh * 8192 + lane];
      peta = eta_buf[(size_t)bh * 8192 + 64 + lane];
    }
  }
  __syncthreads();

  for (int nc = 0; nc < 128; ++nc) {
    const int p = nc & 1;
    const unsigned short* WTc = WT_b[p];
    unsigned short* WTn = WT_b[p ^ 1];

    // ================= phase 1 =================
    if (isA) {
      if (nc) {
#pragma unroll
        for (int n = 0; n < 4; ++n) {
          int e = n * 16 + l15;
          bstv[n] -= bpart[0][e] + bpart[1][e] + bpart[2][e] + bpart[3][e];
        }
      }
      if (nc + 1 < 128) {
#pragma unroll
        for (int j = 0; j < 2; ++j) {
          int rr = rr_ + j * 8;
          *(short8*)&xq_s[p ^ 1][rr * 72 + c8_] = pA0[j];
          *(short8*)&tg_s[p ^ 1][rr * 72 + c8_] = pA1[j];
        }
      }
      if (nc + 2 < 128) {
#pragma unroll
        for (int j = 0; j < 2; ++j) {
          size_t g = (tokb + (nc + 2) * 64 + rr_ + j * 8) * 1024 + col0 + c8_;
          pA0[j] = *(const short8*)&XQ[g];
          pA1[j] = *(const short8*)&TG[g];
        }
      }
      f32x4 accZ[4];
#pragma unroll
      for (int n = 0; n < 4; ++n)
        accZ[n] = (f32x4){bstv[n], bstv[n], bstv[n], bstv[n]};
      __builtin_amdgcn_s_setprio(1);
#pragma unroll
      for (int kk = 0; kk < 2; ++kk) {
        const int ko = kk * 32 + lg * 8;
        short8 a_xk = *(const short8*)&xk_s[p][(q * 16 + l15) * 72 + ko];
#pragma unroll
        for (int n = 0; n < 4; ++n) {
          short8 b_w = *(const short8*)&WTc[(n * 16 + l15) * 72 + ko];
          accZ[n] = __builtin_amdgcn_mfma_f32_16x16x32_bf16(a_xk, b_w, accZ[n], 0, 0, 0);
        }
      }
      __builtin_amdgcn_s_setprio(0);
      float grv[4][4];
#pragma unroll
      for (int j = 0; j < 4; ++j) {
        const int r = q * 16 + lg * 4 + j;
        float z[4], s1 = 0.f, s2 = 0.f;
#pragma unroll
        for (int n = 0; n < 4; ++n) {
          z[n] = accZ[n][j];
          s1 += z[n];
          s2 += z[n] * z[n];
        }
        s1 = dpp16_sum(s1);
        s2 = dpp16_sum(s2);
        float mu = s1 * 0.015625f;
        float var = s2 * 0.015625f - mu * mu;
        float rstd = rsqrtf(var + 1e-6f);
        float xh[4], gx[4], s3 = 0.f, s4 = 0.f;
#pragma unroll
        for (int n = 0; n < 4; ++n) {
          xh[n] = (z[n] - mu) * rstd;
          float tg = bf2f(tg_s[p][r * 72 + n * 16 + l15]);
          float go = gwv[n] * xh[n] + gbv[n] - tg;
          gx[n] = go * gwv[n];
          s3 += gx[n];
          s4 += gx[n] * xh[n];
        }
        s3 = dpp16_sum(s3);
        s4 = dpp16_sum(s4);
#pragma unroll
        for (int n = 0; n < 4; ++n)
          grv[n][j] = (64.f * gx[n] - s3 - xh[n] * s4) * rstd * 0.015625f;
      }
#pragma unroll
      for (int n = 0; n < 4; ++n) {
        us4 pk = {f2bf(grv[n][0]), f2bf(grv[n][1]), f2bf(grv[n][2]),
                  f2bf(grv[n][3])};
        *(us4*)&gradT[(n * 16 + l15) * 72 + q * 16 + lg * 4] = pk;
      }
    } else {
      if (nc + 1 < 128) {
#pragma unroll
        for (int j = 0; j < 2; ++j)
          *(short8*)&xk_s[p ^ 1][(rr_ + j * 8) * 72 + c8_] = pB0[j];
        if (wid == 4) eta_s[p ^ 1][lane] = peta;
      }
      if (nc + 2 < 128) {
#pragma unroll
        for (int j = 0; j < 2; ++j)
          pB0[j] = *(const short8*)
              &XK[(tokb + (nc + 2) * 64 + rr_ + j * 8) * 1024 + col0 + c8_];
        if (wid == 4) peta = eta_buf[(size_t)bh * 8192 + (nc + 2) * 64 + lane];
      }
#pragma unroll
      for (int it = 0; it < 4; ++it) {
        int c0 = q * 16 + it * 4;
        us4 pk;
#pragma unroll
        for (int u = 0; u < 4; ++u)
          pk[u] = f2bf(-eta_s[p][c0 + u] * bf2f(xk_s[p][(c0 + u) * 72 + lane]));
        *(us4*)&xkTe[lane * 72 + c0] = pk;
      }
      f32x4 accA[4];
#pragma unroll
      for (int n = 0; n < 4; ++n) accA[n] = (f32x4){0.f, 0.f, 0.f, 0.f};
      __builtin_amdgcn_s_setprio(1);
#pragma unroll
      for (int kk = 0; kk < 2; ++kk) {
        const int ko = kk * 32 + lg * 8;
        short8 a_xq = *(const short8*)&xq_s[p][(q * 16 + l15) * 72 + ko];
#pragma unroll
        for (int n = 0; n < 4; ++n) {
          short8 b_k = *(const short8*)&xk_s[p][(n * 16 + l15) * 72 + ko];
          accA[n] = __builtin_amdgcn_mfma_f32_16x16x32_bf16(a_xq, b_k, accA[n], 0, 0, 0);
        }
      }
      __builtin_amdgcn_s_setprio(0);
#pragma unroll
      for (int j = 0; j < 4; ++j) {
        const int r = q * 16 + lg * 4 + j;
#pragma unroll
        for (int n = 0; n < 4; ++n) {
          int cj = n * 16 + l15;
          float v = (cj <= r) ? (-eta_s[p][cj] * (1.f + accA[n][j])) : 0.f;
          gc_s[r * 72 + cj] = f2bf(v);
        }
      }
    }
    barrier_fast();  // X

    // ================= phase 2 =================
    if (isA) {
      f32x4 accZb[4];
#pragma unroll
      for (int n = 0; n < 4; ++n)
        accZb[n] = (f32x4){bstv[n], bstv[n], bstv[n], bstv[n]};
      __builtin_amdgcn_s_setprio(1);
#pragma unroll
      for (int kk = 0; kk < 2; ++kk) {
        const int ko = kk * 32 + lg * 8;
        short8 a_xq = *(const short8*)&xq_s[p][(q * 16 + l15) * 72 + ko];
        short8 a_gc = *(const short8*)&gc_s[(q * 16 + l15) * 72 + ko];
#pragma unroll
        for (int n = 0; n < 4; ++n) {
          short8 b_w = *(const short8*)&WTc[(n * 16 + l15) * 72 + ko];
          short8 b_g = *(const short8*)&gradT[(n * 16 + l15) * 72 + ko];
          accZb[n] = __builtin_amdgcn_mfma_f32_16x16x32_bf16(a_xq, b_w, accZb[n], 0, 0, 0);
          accZb[n] = __builtin_amdgcn_mfma_f32_16x16x32_bf16(a_gc, b_g, accZb[n], 0, 0, 0);
        }
      }
      __builtin_amdgcn_s_setprio(0);
#pragma unroll
      for (int j = 0; j < 4; ++j) {
        const int r = q * 16 + lg * 4 + j;
        float z[4], s1 = 0.f, s2 = 0.f;
#pragma unroll
        for (int n = 0; n < 4; ++n) {
          z[n] = accZb[n][j];
          s1 += z[n];
          s2 += z[n] * z[n];
        }
        s1 = dpp16_sum(s1);
        s2 = dpp16_sum(s2);
        float mu = s1 * 0.015625f;
        float var = s2 * 0.015625f - mu * mu;
        float rstd = rsqrtf(var + 1e-6f);
        size_t gbase = (tokb + nc * 64 + r) * 1024 + col0;
#pragma unroll
        for (int n = 0; n < 4; ++n) {
          int e = n * 16 + l15;
          float ov = bf2f(xq_s[p][r * 72 + e]) + gwv[n] * ((z[n] - mu) * rstd) + gbv[n];
          y[gbase + e] = ov;
        }
      }
    } else {
      f32x4 accW[4];
#pragma unroll
      for (int n = 0; n < 4; ++n) accW[n] = Wreg[n];
      __builtin_amdgcn_s_setprio(1);
#pragma unroll
      for (int kk = 0; kk < 2; ++kk) {
        const int ko = kk * 32 + lg * 8;
        short8 a_ke = *(const short8*)&xkTe[(q * 16 + l15) * 72 + ko];
#pragma unroll
        for (int n = 0; n < 4; ++n) {
          short8 b_g = *(const short8*)&gradT[(n * 16 + l15) * 72 + ko];
          accW[n] = __builtin_amdgcn_mfma_f32_16x16x32_bf16(a_ke, b_g, accW[n], 0, 0, 0);
        }
      }
      __builtin_amdgcn_s_setprio(0);
#pragma unroll
      for (int n = 0; n < 4; ++n) {
        Wreg[n] = accW[n];
        us4 pk = {f2bf(accW[n][0]), f2bf(accW[n][1]), f2bf(accW[n][2]),
                  f2bf(accW[n][3])};
        *(us4*)&WTn[(n * 16 + l15) * 72 + q * 16 + lg * 4] = pk;
      }
      {
        float s = 0.f;
#pragma unroll
        for (int it = 0; it < 4; ++it) {
          us4 gv = *(const us4*)&gradT[lane * 72 + q * 16 + it * 4];
#pragma unroll
          for (int u = 0; u < 4; ++u)
            s += eta_s[p][q * 16 + it * 4 + u] * bf2f(gv[u]);
        }
        bpart[q][lane] = s;
      }
    }
    barrier_fast();  // Y
  }
}

// ---------------- stage 4: post layernorm over D=1024 ----------------
__global__ __launch_bounds__(256) void postnorm(
    const float* __restrict__ yv, const float* __restrict__ pw,
    const float* __restrict__ pb, unsigned short* __restrict__ yn) {
  int t = blockIdx.x;
  int tid = threadIdx.x, lane = tid & 63, wid = tid >> 6;
  const float* row = yv + (size_t)t * 1024;
  float4 v = *(const float4*)&row[tid * 4];
  float s1 = v.x + v.y + v.z + v.w;
  float s2 = v.x * v.x + v.y * v.y + v.z * v.z + v.w * v.w;
#pragma unroll
  for (int o = 1; o < 64; o <<= 1) {
    s1 += __shfl_xor(s1, o);
    s2 += __shfl_xor(s2, o);
  }
  __shared__ float r1[4], r2[4];
  if (lane == 0) {
    r1[wid] = s1;
    r2[wid] = s2;
  }
  __syncthreads();
  s1 = r1[0] + r1[1] + r1[2] + r1[3];
  s2 = r2[0] + r2[1] + r2[2] + r2[3];
  float mu = s1 * (1.f / 1024.f);
  float var = s2 * (1.f / 1024.f) - mu * mu;
  float rstd = rsqrtf(var + 1e-6f);
  int c = tid * 4;
  us4 o4 = {f2bf(pw[c] * ((v.x - mu) * rstd) + pb[c]),
            f2bf(pw[c + 1] * ((v.y - mu) * rstd) + pb[c + 1]),
            f2bf(pw[c + 2] * ((v.z - mu) * rstd) + pb[c + 2]),
            f2bf(pw[c + 3] * ((v.w - mu) * rstd) + pb[c + 3])};
  *(us4*)&yn[(size_t)t * 1024 + c] = o4;
}

// ---------------------------------------------------------------------------
extern "C" void kernel_launch(void* const* d_in, const int* in_sizes, int n_in,
                              void* d_out, int out_size, void* d_ws,
                              size_t ws_size, hipStream_t stream) {
  const float* hs  = (const float*)d_in[0];
  const float* wqw = (const float*)d_in[1];
  const float* wqb = (const float*)d_in[2];
  const float* wkw = (const float*)d_in[3];
  const float* wkb = (const float*)d_in[4];
  const float* wvw = (const float*)d_in[5];
  const float* wvb = (const float*)d_in[6];
  const float* wow = (const float*)d_in[7];
  const float* wob = (const float*)d_in[8];
  const float* tnw = (const float*)d_in[9];
  const float* tnb = (const float*)d_in[10];
  const float* lrw = (const float*)d_in[11];
  const float* lrb = (const float*)d_in[12];
  const float* W1  = (const float*)d_in[13];
  const float* b1  = (const float*)d_in[14];
  const float* pnw = (const float*)d_in[15];
  const float* pnb = (const float*)d_in[16];

  // workspace layout (bytes); XQn aliases hs_bf (dead after QKV GEMM)
  const size_t OFF_WCAT  = 67108864;                        // 3328*1024*2
  const size_t OFF_BIASC = OFF_WCAT + 6815744;
  const size_t OFF_WOBF  = OFF_BIASC + 16384;
  const size_t OFF_QKVL  = OFF_WOBF + 2097152;              // 32768*3328*2
  const size_t OFF_XK    = OFF_QKVL + 218103808;
  const size_t OFF_TGT   = OFF_XK + 67108864;
  const size_t OFF_ETA   = OFF_TGT + 67108864;
  const size_t NEEDED    = OFF_ETA + 2097152;
  if (ws_size < NEEDED) return;

  char* ws = (char*)d_ws;
  unsigned short* hs_bf = (unsigned short*)ws;
  unsigned short* XQn   = (unsigned short*)ws;              // alias (after gemm)
  unsigned short* Wcat  = (unsigned short*)(ws + OFF_WCAT);
  float* biasc          = (float*)(ws + OFF_BIASC);
  unsigned short* wo_bf = (unsigned short*)(ws + OFF_WOBF);
  unsigned short* QKVL  = (unsigned short*)(ws + OFF_QKVL);
  float* yv             = (float*)(ws + OFF_QKVL);          // alias (after stage2)
  unsigned short* ynorm = (unsigned short*)(ws + OFF_QKVL + 134217728);
  unsigned short* XKn   = (unsigned short*)(ws + OFF_XK);
  unsigned short* TGT   = (unsigned short*)(ws + OFF_TGT);
  float* eta_buf        = (float*)(ws + OFF_ETA);

  cvt_f32_bf16<<<32768, 256, 0, stream>>>(hs, hs_bf, 33554432L);
  build_wcat<<<13312, 256, 0, stream>>>(wqw, wkw, wvw, lrw, wqb, wkb, wvb, lrb,
                                        Wcat, biasc);
  cvt_f32_bf16<<<1024, 256, 0, stream>>>(wow, wo_bf, 1048576L);
  gemm256<1><<<1664, 512, 0, stream>>>(hs_bf, Wcat, biasc, QKVL,
                                       32768L, 3328L, 1024L, 13, 3328L);
  stage2<<<131072, 256, 0, stream>>>(QKVL, tnw, tnb, XQn, XKn, TGT, eta_buf);
  ttt_scan<<<64, 512, 0, stream>>>(XQn, XKn, TGT, eta_buf, W1, b1, tnw, tnb, yv);
  postnorm<<<32768, 256, 0, stream>>>(yv, pnw, pnb, ynorm);
  gemm256<0><<<512, 512, 0, stream>>>(ynorm, wo_bf, wob, d_out,
                                      32768L, 1024L, 1024L, 4, 1024L);
}